// Round 11
// baseline (1522.976 us; speedup 1.0000x reference)
//
#include <hip/hip_runtime.h>
#include <hip/hip_bf16.h>
#include <cstdint>
#include <cstddef>

using bf16 = __hip_bfloat16;

static constexpr int BBATCH = 8, CCH = 64, NNODE = 170, TT = 256;
static constexpr size_t HSZ  = (size_t)BBATCH * CCH * NNODE * TT;  // 22282240
static constexpr size_t H7SZ = (size_t)CCH * NNODE * TT;           // 2785280
static constexpr int GN = NNODE * NNODE;                           // 28900

typedef __attribute__((ext_vector_type(8))) short short8v;
typedef __attribute__((ext_vector_type(4))) float f32x4;

__device__ __forceinline__ float b2f(bf16 v) { return __bfloat162float(v); }
__device__ __forceinline__ bf16  f2b(float v) { return __float2bfloat16(v); }

union BfU { bf16 h; unsigned short s; };
__device__ __forceinline__ unsigned short bfbits(float v) { BfU u; u.h = f2b(v); return u.s; }
__device__ __forceinline__ unsigned pack2(float a, float b) {
  return ((unsigned)bfbits(b) << 16) | bfbits(a);
}
__device__ __forceinline__ unsigned pks(short lo, short hi) {
  return ((unsigned)(unsigned short)hi << 16) | (unsigned short)lo;
}
__device__ __forceinline__ float shortbf(short s) { BfU u; u.s = (unsigned short)s; return b2f(u.h); }

// fast tanh for the VALUE path only (b<7): ~1e-6 rel err, correct saturation.
__device__ __forceinline__ float tanhfast(float v) {
  float e = __expf(2.f * v);
  return 1.f - 2.f / (e + 1.f);
}

// ---------------- threefry2x32 (JAX-compatible, partitionable) ----------------
__device__ __forceinline__ unsigned rotl32(unsigned v, int d) { return (v << d) | (v >> (32 - d)); }

__device__ void threefry2x32(unsigned k0, unsigned k1, unsigned x0, unsigned x1,
                             unsigned& y0, unsigned& y1) {
  unsigned ks0 = k0, ks1 = k1, ks2 = k0 ^ k1 ^ 0x1BD11BDAu;
  x0 += ks0; x1 += ks1;
  const int ra[4] = {13, 15, 26, 6};
  const int rb[4] = {17, 29, 16, 24};
#pragma unroll
  for (int r = 0; r < 4; r++) { x0 += x1; x1 = rotl32(x1, ra[r]); x1 ^= x0; }
  x0 += ks1; x1 += ks2 + 1u;
#pragma unroll
  for (int r = 0; r < 4; r++) { x0 += x1; x1 = rotl32(x1, rb[r]); x1 ^= x0; }
  x0 += ks2; x1 += ks0 + 2u;
#pragma unroll
  for (int r = 0; r < 4; r++) { x0 += x1; x1 = rotl32(x1, ra[r]); x1 ^= x0; }
  x0 += ks0; x1 += ks1 + 3u;
#pragma unroll
  for (int r = 0; r < 4; r++) { x0 += x1; x1 = rotl32(x1, rb[r]); x1 ^= x0; }
  x0 += ks1; x1 += ks2 + 4u;
#pragma unroll
  for (int r = 0; r < 4; r++) { x0 += x1; x1 = rotl32(x1, ra[r]); x1 ^= x0; }
  x0 += ks2; x1 += ks0 + 5u;
  y0 = x0; y1 = x1;
}

__global__ void k_keys(unsigned* keys) {
  int j = threadIdx.x;
  if (j < 4) {
    unsigned y0, y1;
    threefry2x32(0u, 42u, 0u, (unsigned)j, y0, y1);
    keys[2*j] = y0; keys[2*j+1] = y1;
  }
}

__global__ __launch_bounds__(256) void k_gumbel(const unsigned* __restrict__ keys,
                                                float* __restrict__ g) {
  int idx = blockIdx.x * 256 + threadIdx.x;
  if (idx >= 4 * GN) return;
  int w = idx / GN, i = idx % GN;
  unsigned y0, y1;
  threefry2x32(keys[2*w], keys[2*w+1], 0u, (unsigned)i, y0, y1);
  unsigned bits = y0 ^ y1;
  unsigned fb = (bits >> 9) | 0x3f800000u;
  float u = __uint_as_float(fb) - 1.0f;
  g[idx] = -logf(-logf(u + 1e-20f) + 1e-20f);
}

// ---------------- adj = softmax(relu(nv1@nv2), axis=1) ----------------
__global__ __launch_bounds__(256) void k_adj(const float* __restrict__ nv1,
                                             const float* __restrict__ nv2,
                                             float* __restrict__ adj) {
  int i = blockIdx.x, j = threadIdx.x;
  __shared__ float red[256];
  float val = 0.f, r = -1e30f;
  if (j < NNODE) {
    float acc = 0.f;
    for (int k = 0; k < 10; k++) acc += nv1[i*10+k] * nv2[k*NNODE+j];
    val = acc > 0.f ? acc : 0.f;
    r = val;
  }
  red[j] = r; __syncthreads();
  for (int s = 128; s; s >>= 1) { if (j < s) red[j] = fmaxf(red[j], red[j+s]); __syncthreads(); }
  float m = red[0]; __syncthreads();
  float e = (j < NNODE) ? expf(val - m) : 0.f;
  red[j] = e; __syncthreads();
  for (int s = 128; s; s >>= 1) { if (j < s) red[j] += red[j+s]; __syncthreads(); }
  if (j < NNODE) adj[i*NNODE+j] = e / red[0];
}

// ---------------- weight repacks ----------------
__global__ __launch_bounds__(256) void k_rep5T(const float* __restrict__ w, float* __restrict__ out) {
  int idx = blockIdx.x * 256 + threadIdx.x;
  if (idx >= 64*64*5) return;
  int oc = idx / 5, k = idx - oc * 5;
  int o = oc >> 6, c = oc & 63;
  out[(c*5 + k)*64 + o] = w[idx];
}
__global__ __launch_bounds__(256) void k_rep3T(const float* __restrict__ w, float* __restrict__ out) {
  int idx = blockIdx.x * 256 + threadIdx.x;
  if (idx >= 64*64*3) return;
  int oc = idx / 3, k = idx - oc * 3;
  int o = oc >> 6, c = oc & 63;
  out[(c*3 + k)*64 + o] = w[idx];
}
// mfma A-fragment packs
__global__ __launch_bounds__(256) void k_pack5(const float* __restrict__ w, short* __restrict__ out) {
  int idx = blockIdx.x * 256 + threadIdx.x;
  if (idx >= 20480) return;
  int j = idx & 7, l = (idx >> 3) & 63, mi = (idx >> 9) & 3, ks = (idx >> 11) & 1, k = idx >> 12;
  int o = mi*16 + (l & 15);
  int c = ks*32 + (l >> 4)*8 + j;
  out[idx] = (short)bfbits(w[(o*64 + c)*5 + k]);
}
__global__ __launch_bounds__(256) void k_pack3(const float* __restrict__ w, short* __restrict__ out) {
  int idx = blockIdx.x * 256 + threadIdx.x;
  if (idx >= 12288) return;
  int j = idx & 7, l = (idx >> 3) & 63, mi = (idx >> 9) & 3, ks = (idx >> 11) & 1, k = idx >> 12;
  int o = mi*16 + (l & 15);
  int c = ks*32 + (l >> 4)*8 + j;
  out[idx] = (short)bfbits(w[(o*64 + c)*3 + k]);
}
// dcw (o,128) -> A-fragments, 4 K-steps
__global__ __launch_bounds__(256) void k_packM(const float* __restrict__ w, short* __restrict__ out) {
  int idx = blockIdx.x * 256 + threadIdx.x;
  if (idx >= 8192) return;
  int j = idx & 7, l = (idx >> 3) & 63, mi = (idx >> 9) & 3, kk = idx >> 11;
  int o = mi*16 + (l & 15);
  int c = kk*32 + (l >> 4)*8 + j;
  out[idx] = (short)bfbits(w[o*128 + c]);
}
// dadj^T -> A-fragments: A[m][n] = dadj[n][m]; 11 m-tiles x 6 k-steps, zero-padded
__global__ __launch_bounds__(256) void k_packD(const float* __restrict__ dadj, short* __restrict__ out) {
  int idx = blockIdx.x * 256 + threadIdx.x;
  if (idx >= 33792) return;   // 11*6*64*8
  int j = idx & 7, l = (idx >> 3) & 63;
  int g = idx >> 9;           // mi*6 + ks
  int ks = g % 6, mi = g / 6;
  int m = mi*16 + (l & 15);
  int n = ks*32 + (l >> 4)*8 + j;
  float v = (m < NNODE && n < NNODE) ? dadj[n*NNODE + m] : 0.f;
  out[idx] = (short)bfbits(v);
}

// ---------------- branch (b<7): bf16 MFMA implicit-GEMM, 17.4 KB LDS ----------------
// grid (170, 4, 7), block 256 = 4 waves.
__global__ __launch_bounds__(256) void k_branchM(
    const float* __restrict__ src, int par,
    const float* __restrict__ b5, const float* __restrict__ b3,
    const short* __restrict__ wp5, const short* __restrict__ wp3,
    bf16* __restrict__ hout) {
  const int n = blockIdx.x, q = blockIdx.y, b = blockIdx.z;
  const int tid = threadIdx.x;
  const int l = tid & 63;
  const int mi = __builtin_amdgcn_readfirstlane(tid >> 6);
  const int t0 = q * 64;
  __shared__ char lds[17408];   // xT rows0-69 @0 (8960B); h1T rows0-65 @8960 (8448B); out tile @0 (9216B)

  // stage xT (bf16, swizzled), c-pairs -> uint writes
  {
    int t = t0 + l - 3; t = t < 0 ? 0 : (t > 255 ? 255 : t);
#pragma unroll
    for (int it = 0; it < 8; it++) {
      int c0 = it * 8 + mi * 2;
      size_t sb = ((size_t)b * 64 + c0) * NNODE + n;
      float v0, v1;
      if (par >= 0) { v0 = src[sb * 512 + 2*t + par]; v1 = src[(sb + NNODE) * 512 + 2*t + par]; }
      else          { v0 = src[sb * 256 + t];         v1 = src[(sb + NNODE) * 256 + t]; }
      *(unsigned*)(lds + l*128 + ((2*c0) ^ ((l & 7) << 4))) = pack2(v0, v1);
    }
  }
  // halo rows 64..69
  if (tid < 192) {
    int tr = 64 + (tid >> 5);
    int c0 = (tid & 31) * 2;
    int t = t0 + tr - 3; if (t > 255) t = 255;
    size_t sb = ((size_t)b * 64 + c0) * NNODE + n;
    float v0, v1;
    if (par >= 0) { v0 = src[sb * 512 + 2*t + par]; v1 = src[(sb + NNODE) * 512 + 2*t + par]; }
    else          { v0 = src[sb * 256 + t];         v1 = src[(sb + NNODE) * 256 + t]; }
    *(unsigned*)(lds + tr*128 + ((2*c0) ^ ((tr & 7) << 4))) = pack2(v0, v1);
  }
  __syncthreads();

  // conv5: 5 taps x 2 K-steps x (4 main + 1 halo) tiles
  f32x4 acc[5];
#pragma unroll
  for (int i = 0; i < 5; i++) acc[i] = (f32x4){0.f, 0.f, 0.f, 0.f};
  for (int k = 0; k < 5; k++) {
#pragma unroll
    for (int ks = 0; ks < 2; ks++) {
      short8v af = *(const short8v*)(wp5 + (size_t)((((k*2 + ks)*4 + mi)*64 + l) * 8));
      const int c0 = ks*32 + (l >> 4)*8;
#pragma unroll
      for (int ni = 0; ni < 5; ni++) {
        int tr = ni*16 + (l & 15) + k;
        short8v bf = *(const short8v*)(lds + tr*128 + ((2*c0) ^ ((tr & 7) << 4)));
        acc[ni] = __builtin_amdgcn_mfma_f32_16x16x32_bf16(af, bf, acc[ni], 0, 0, 0);
      }
    }
  }
  {
    const int o0 = mi*16 + ((l >> 4) << 2);
    float4 bv = *(const float4*)&b5[o0];
    float bb[4] = {bv.x, bv.y, bv.z, bv.w};
#pragma unroll
    for (int ni = 0; ni < 4; ni++) {
      int tr = ni*16 + (l & 15);
      float v[4];
#pragma unroll
      for (int r = 0; r < 4; r++) {
        float u = acc[ni][r] + bb[r];
        v[r] = u >= 0.f ? u : 0.01f * u;
      }
      int colb = (2*o0) ^ ((tr & 7) << 4);
      *(uint2*)(lds + 8960 + tr*128 + colb) = make_uint2(pack2(v[0], v[1]), pack2(v[2], v[3]));
    }
    if ((l & 15) < 2) {
      int tr = 64 + (l & 15);
      float v[4];
#pragma unroll
      for (int r = 0; r < 4; r++) {
        float u = acc[4][r] + bb[r];
        v[r] = u >= 0.f ? u : 0.01f * u;
      }
      int colb = (2*o0) ^ ((tr & 7) << 4);
      *(uint2*)(lds + 8960 + tr*128 + colb) = make_uint2(pack2(v[0], v[1]), pack2(v[2], v[3]));
    }
  }
  __syncthreads();

  // conv3: 3 taps x 2 K-steps x 4 tiles
  f32x4 acc3[4];
#pragma unroll
  for (int i = 0; i < 4; i++) acc3[i] = (f32x4){0.f, 0.f, 0.f, 0.f};
  for (int k = 0; k < 3; k++) {
#pragma unroll
    for (int ks = 0; ks < 2; ks++) {
      short8v af = *(const short8v*)(wp3 + (size_t)((((k*2 + ks)*4 + mi)*64 + l) * 8));
      const int c0 = ks*32 + (l >> 4)*8;
#pragma unroll
      for (int ni = 0; ni < 4; ni++) {
        int tr = ni*16 + (l & 15) + k;
        short8v bf = *(const short8v*)(lds + 8960 + tr*128 + ((2*c0) ^ ((tr & 7) << 4)));
        acc3[ni] = __builtin_amdgcn_mfma_f32_16x16x32_bf16(af, bf, acc3[ni], 0, 0, 0);
      }
    }
  }
  {
    const int o0 = mi*16 + ((l >> 4) << 2);
    float4 bv = *(const float4*)&b3[o0];
    float bb[4] = {bv.x, bv.y, bv.z, bv.w};
    __syncthreads();   // conv3 LDS reads done before out-tile overwrites region @0
#pragma unroll
    for (int ni = 0; ni < 4; ni++) {
      int t = ni*16 + (l & 15);
#pragma unroll
      for (int r = 0; r < 4; r++) {
        float v = tanhfast(acc3[ni][r] + bb[r]);
        *(short*)(lds + (o0 + r)*144 + t*2) = (short)bfbits(v);
      }
    }
  }
  __syncthreads();

  {
    const int ro = tid >> 2, rq = tid & 3;
    uint4 p0 = *(const uint4*)(lds + ro*144 + rq*32);
    uint4 p1 = *(const uint4*)(lds + ro*144 + rq*32 + 16);
    bf16* dst = hout + (((size_t)b * 64 + ro) * NNODE + n) * TT + t0 + rq*16;
    *(uint4*)&dst[0] = p0;
    *(uint4*)&dst[8] = p1;
  }
}

// ---------------- branch (b==7): exact fp32 path (argmax chain), unchanged ----------------
// grid (170, 4), block 256.
__global__ __launch_bounds__(256) void k_branch7(
    const float* __restrict__ src, int par,
    const float* __restrict__ wT5, const float* __restrict__ b5,
    const float* __restrict__ wT3, const float* __restrict__ b3,
    float* __restrict__ h7f, float* __restrict__ Spart) {
  const int n = blockIdx.x, q = blockIdx.y;
  const int tid = threadIdx.x;
  const int l = tid & 63;
  const int w = __builtin_amdgcn_readfirstlane(tid >> 6);
  const int t0 = q * 64;
  __shared__ char lds[35840];
  float (*xs)[72]  = (float(*)[72])lds;
  float (*h1s)[68] = (float(*)[68])(lds + 18432);
  const int o = l;
  const int base = w * 16;
  const bool w3x = (w == 3);

  for (int i = tid; i < 64 * 70; i += 256) {
    int c = i / 70, pl = i - c * 70;
    int t = t0 + pl - 3; t = t < 0 ? 0 : (t > 255 ? 255 : t);
    size_t sb = ((size_t)7 * 64 + c) * NNODE + n;
    xs[c][pl] = (par >= 0) ? src[sb * 512 + 2 * t + par] : src[sb * 256 + t];
  }
  __syncthreads();

  {
    float acc[16];
#pragma unroll
    for (int tt = 0; tt < 16; tt++) acc[tt] = 0.f;
    float aH0 = 0.f, aH1 = 0.f;
    const float* wp = wT5 + o;
    for (int c = 0; c < 64; c++) {
      float xv[22];
      float4 v0 = *(const float4*)&xs[c][base + 0];
      float4 v1 = *(const float4*)&xs[c][base + 4];
      float4 v2 = *(const float4*)&xs[c][base + 8];
      float4 v3 = *(const float4*)&xs[c][base + 12];
      float4 v4 = *(const float4*)&xs[c][base + 16];
      xv[0]=v0.x; xv[1]=v0.y; xv[2]=v0.z; xv[3]=v0.w;
      xv[4]=v1.x; xv[5]=v1.y; xv[6]=v1.z; xv[7]=v1.w;
      xv[8]=v2.x; xv[9]=v2.y; xv[10]=v2.z; xv[11]=v2.w;
      xv[12]=v3.x; xv[13]=v3.y; xv[14]=v3.z; xv[15]=v3.w;
      xv[16]=v4.x; xv[17]=v4.y; xv[18]=v4.z; xv[19]=v4.w;
      if (w3x) { float2 vt = *(const float2*)&xs[c][68]; xv[20]=vt.x; xv[21]=vt.y; }
      float w0 = wp[0], w1 = wp[64], w2 = wp[128], w3_ = wp[192], w4 = wp[256];
      wp += 320;
#pragma unroll
      for (int tt = 0; tt < 16; tt++)
        acc[tt] += w0*xv[tt] + w1*xv[tt+1] + w2*xv[tt+2] + w3_*xv[tt+3] + w4*xv[tt+4];
      if (w3x) {
        aH0 += w0*xv[16] + w1*xv[17] + w2*xv[18] + w3_*xv[19] + w4*xv[20];
        aH1 += w0*xv[17] + w1*xv[18] + w2*xv[19] + w3_*xv[20] + w4*xv[21];
      }
    }
    float bias = b5[o];
#pragma unroll
    for (int tt = 0; tt < 16; tt++) {
      float v = acc[tt] + bias;
      h1s[o][base + tt] = v >= 0.f ? v : 0.01f * v;
    }
    if (w3x) {
      float u0 = aH0 + bias, u1 = aH1 + bias;
      h1s[o][64] = u0 >= 0.f ? u0 : 0.01f * u0;
      h1s[o][65] = u1 >= 0.f ? u1 : 0.01f * u1;
    }
  }
  __syncthreads();

  {
    float acc[16];
#pragma unroll
    for (int tt = 0; tt < 16; tt++) acc[tt] = 0.f;
    const float* wp = wT3 + o;
    for (int c = 0; c < 64; c++) {
      float hv[18];
      float4 v0 = *(const float4*)&h1s[c][base + 0];
      float4 v1 = *(const float4*)&h1s[c][base + 4];
      float4 v2 = *(const float4*)&h1s[c][base + 8];
      float4 v3 = *(const float4*)&h1s[c][base + 12];
      float4 v4 = *(const float4*)&h1s[c][base + 16];
      hv[0]=v0.x; hv[1]=v0.y; hv[2]=v0.z; hv[3]=v0.w;
      hv[4]=v1.x; hv[5]=v1.y; hv[6]=v1.z; hv[7]=v1.w;
      hv[8]=v2.x; hv[9]=v2.y; hv[10]=v2.z; hv[11]=v2.w;
      hv[12]=v3.x; hv[13]=v3.y; hv[14]=v3.z; hv[15]=v3.w;
      hv[16]=v4.x; hv[17]=v4.y;
      float w0 = wp[0], w1 = wp[64], w2 = wp[128];
      wp += 192;
#pragma unroll
      for (int tt = 0; tt < 16; tt++)
        acc[tt] += w0*hv[tt] + w1*hv[tt+1] + w2*hv[tt+2];
    }
    float bias = b3[o];
#pragma unroll
    for (int tt = 0; tt < 16; tt++) acc[tt] = tanhf(acc[tt] + bias);
    __syncthreads();
#pragma unroll
    for (int tt = 0; tt < 16; tt++) xs[o][base + tt] = acc[tt];
  }
  __syncthreads();

  {
    const int ro = tid >> 2, rq = tid & 3;
    float4 v0 = *(const float4*)&xs[ro][rq*16 + 0];
    float4 v1 = *(const float4*)&xs[ro][rq*16 + 4];
    float4 v2 = *(const float4*)&xs[ro][rq*16 + 8];
    float4 v3 = *(const float4*)&xs[ro][rq*16 + 12];
    float* dst = h7f + ((size_t)ro * NNODE + n) * TT + t0 + rq*16;
    *(float4*)&dst[0] = v0; *(float4*)&dst[4] = v1;
    *(float4*)&dst[8] = v2; *(float4*)&dst[12] = v3;
    float s = v0.x+v0.y+v0.z+v0.w + v1.x+v1.y+v1.z+v1.w
            + v2.x+v2.y+v2.z+v2.w + v3.x+v3.y+v3.z+v3.w;
    s += __shfl_xor(s, 1, 4);
    s += __shfl_xor(s, 2, 4);
    if (rq == 0) Spart[(q * 64 + ro) * NNODE + n] = s;
  }
}

// ---------------- ST[n][c] = sum_q Spart ----------------
__global__ __launch_bounds__(256) void k_sredT(const float* __restrict__ Spart, float* __restrict__ ST) {
  int idx = blockIdx.x * 256 + threadIdx.x;
  if (idx >= CCH * NNODE) return;
  int nn = idx >> 6, c = idx & 63;
  float acc = 0.f;
#pragma unroll
  for (int qq = 0; qq < 4; qq++) acc += Spart[(qq * 64 + c) * NNODE + nn];
  ST[idx] = acc;
}

// ---------------- fused S1 + H0 ----------------
__global__ __launch_bounds__(64) void k_s1h0(const float* __restrict__ ST, const float* __restrict__ adj,
                                             const float* __restrict__ ggw, const float* __restrict__ ggb,
                                             float* __restrict__ H0) {
  const int n = blockIdx.x;
  const int tid = threadIdx.x;
  __shared__ float s1[64], sc[64];
  {
    const int c = tid;
    float acc = 0.f;
    for (int nn = 0; nn < NNODE; nn++) acc += ST[nn*64 + c] * adj[nn*NNODE + n];
    s1[c] = acc;
    sc[c] = ST[n*64 + c];
  }
  __syncthreads();
  {
    const int o = tid;
    float acc = 256.f * ggb[o];
    for (int c = 0; c < 64; c++)
      acc += ggw[o*128 + c] * sc[c] + ggw[o*128 + 64 + c] * s1[c];
    H0[n*64 + o] = acc;
  }
}

// ---------------- fused fc0+fc1+fc2 + gumbel-argmax + dadj ----------------
__global__ __launch_bounds__(256) void k_fc(const float* __restrict__ H0,
    const float* __restrict__ fc0w, const float* __restrict__ fc0b,
    const float* __restrict__ fc1w, const float* __restrict__ fc1b,
    const float* __restrict__ fc2w, const float* __restrict__ fc2b,
    const float* __restrict__ g, const float* __restrict__ adj,
    const float* __restrict__ a_in,
    float* __restrict__ dadj, float* __restrict__ out_tail) {
  const int i = blockIdx.x;
  const int tid = threadIdx.x;
  __shared__ float h0r[64];
  __shared__ float a1r[NNODE];
  __shared__ float a2r[340];
  __shared__ float vred[256];
  __shared__ int ired[256];
  if (tid < 64) h0r[tid] = H0[i*64 + tid];
  __syncthreads();
  if (tid < NNODE) {
    float acc = fc0b[tid];
    for (int o = 0; o < 64; o++) acc += h0r[o] * fc0w[tid*64 + o];
    a1r[tid] = tanhf(acc);
  }
  __syncthreads();
  for (int j = tid; j < 340; j += 256) {
    float acc = fc1b[j];
    for (int k = 0; k < NNODE; k++) acc += a1r[k] * fc1w[j*NNODE + k];
    a2r[j] = tanhf(acc);
  }
  __syncthreads();
  float v = -1e30f;
  if (tid < NNODE) {
    float acc = fc2b[tid];
    for (int k = 0; k < 340; k++) acc += a2r[k] * fc2w[tid*340 + k];
    v = tanhf(acc) + g[i*NNODE + tid];
  }
  vred[tid] = v; ired[tid] = tid;
  __syncthreads();
  for (int s = 128; s; s >>= 1) {
    if (tid < s) {
      if (vred[tid+s] > vred[tid]) { vred[tid] = vred[tid+s]; ired[tid] = ired[tid+s]; }
    }
    __syncthreads();
  }
  int jmax = ired[0];
  float a = a_in[0];
  if (tid < NNODE) {
    float la = (tid == jmax && jmax != i) ? 1.f : 0.f;
    float dv = la * a + adj[i*NNODE + tid] * (1.f - a);
    dadj[i*NNODE + tid] = dv;
    if (out_tail) out_tail[i*NNODE + tid] = dv;
  }
}

// ---------------- hA (b<7) via MFMA: D[m][t] = sum_n dadjT[m][n] h[n][t] ----------------
__global__ __launch_bounds__(256) void k_hA_m(const bf16* __restrict__ h, const short* __restrict__ dP,
                                              bf16* __restrict__ hA) {
  const int bc = blockIdx.x, tq = blockIdx.y;
  const int tid = threadIdx.x;
  const int l = tid & 63;
  const int w = __builtin_amdgcn_readfirstlane(tid >> 6);
  const int t0 = tq * 64;
  __shared__ char lds[25600];

  const bf16* hp = h + (size_t)bc * NNODE * TT;
  for (int i = tid; i < 170*64; i += 256) {
    int n = i >> 6, t = i & 63;
    *(short*)(lds + t*400 + ((2*n) ^ ((t & 7) << 4))) = *(const short*)&hp[(size_t)n * TT + t0 + t];
  }
  for (int i = tid; i < 22*64; i += 256) {
    int n = 170 + (i >> 6), t = i & 63;
    *(short*)(lds + t*400 + ((2*n) ^ ((t & 7) << 4))) = 0;
  }
  __syncthreads();

  f32x4 acc[11];
#pragma unroll
  for (int i = 0; i < 11; i++) acc[i] = (f32x4){0.f, 0.f, 0.f, 0.f};
  const int tr = w*16 + (l & 15);
#pragma unroll
  for (int ks = 0; ks < 6; ks++) {
    const int n0 = ks*32 + (l >> 4)*8;
    short8v bf = *(const short8v*)(lds + tr*400 + ((2*n0) ^ ((tr & 7) << 4)));
#pragma unroll
    for (int mi = 0; mi < 11; mi++) {
      short8v af = *(const short8v*)(dP + (size_t)(((mi*6 + ks)*64 + l) * 8));
      acc[mi] = __builtin_amdgcn_mfma_f32_16x16x32_bf16(af, bf, acc[mi], 0, 0, 0);
    }
  }

  bf16* dst = hA + (size_t)bc * NNODE * TT + t0 + w*16 + (l & 15);
#pragma unroll
  for (int mi = 0; mi < 11; mi++) {
#pragma unroll
    for (int r = 0; r < 4; r++) {
      int m = mi*16 + ((l >> 4) << 2) + r;
      if (m < NNODE) dst[(size_t)m * TT] = f2b(acc[mi][r]);
    }
  }
}

// ---------------- hA (b==7): exact fp32 path ----------------
__global__ __launch_bounds__(256) void k_hA7(const float* __restrict__ h7f,
                                             const float* __restrict__ dadj,
                                             float* __restrict__ hA7f) {
  const int c = blockIdx.x, tq = blockIdx.y;
  const int t0 = tq * 32;
  const int tid = threadIdx.x;
  const int lane = tid & 63;
  const int w = __builtin_amdgcn_readfirstlane(tid >> 6);
  __shared__ float hs[170][33];
  for (int i = tid; i < 170*32; i += 256) {
    int nn = i >> 5, tl = i & 31;
    hs[nn][tl] = h7f[((size_t)c * NNODE + nn) * TT + t0 + tl];
  }
  __syncthreads();
  float acc0[8], acc1[8], acc2[8];
#pragma unroll
  for (int tt = 0; tt < 8; tt++) { acc0[tt] = 0.f; acc1[tt] = 0.f; acc2[tt] = 0.f; }
  const int toff = w * 8;
  for (int nn = 0; nn < NNODE; nn++) {
    float hv[8];
#pragma unroll
    for (int tt = 0; tt < 8; tt++) hv[tt] = hs[nn][toff + tt];
    const float* dr = &dadj[nn * NNODE];
    float w0 = dr[lane];
    float w1 = dr[64 + lane];
    float w2 = (lane < 42) ? dr[128 + lane] : 0.f;
#pragma unroll
    for (int tt = 0; tt < 8; tt++) {
      acc0[tt] += w0 * hv[tt];
      acc1[tt] += w1 * hv[tt];
      acc2[tt] += w2 * hv[tt];
    }
  }
  __syncthreads();
#pragma unroll
  for (int tt = 0; tt < 8; tt++) {
    hs[lane][toff + tt] = acc0[tt];
    hs[64 + lane][toff + tt] = acc1[tt];
    if (lane < 42) hs[128 + lane][toff + tt] = acc2[tt];
  }
  __syncthreads();
  if (tid < NNODE) {
    float* dst = hA7f + ((size_t)c * NNODE + tid) * TT + t0;
#pragma unroll
    for (int j = 0; j < 8; j++)
      *(float4*)&dst[j*4] = make_float4(hs[tid][j*4], hs[tid][j*4+1], hs[tid][j*4+2], hs[tid][j*4+3]);
  }
}

// ---------------- channel mix (b<7): bf16 MFMA GEMM ----------------
__global__ __launch_bounds__(256) void k_mix_m(const bf16* __restrict__ h, const bf16* __restrict__ hA,
                                               const short* __restrict__ dcwP, const float* __restrict__ dcb,
                                               const float* __restrict__ x,
                                               float* __restrict__ oute, float* __restrict__ outo, int epi) {
  const int n = blockIdx.x, b = blockIdx.y, tq = blockIdx.z;
  const int tid = threadIdx.x;
  const int l = tid & 63;
  const int mi = __builtin_amdgcn_readfirstlane(tid >> 6);
  const int t0 = tq * 64;
  __shared__ char lds[16384];

#pragma unroll
  for (int it = 0; it < 8; it++) {
    int c0 = it * 8 + mi * 2;
    size_t off = (((size_t)b * 64 + c0) * NNODE + n) * TT + t0 + l;
    size_t off1 = off + (size_t)NNODE * TT;
    *(unsigned*)(lds + l*256 + ((2*c0) ^ ((l & 7) << 4))) =
        pks(*(const short*)&h[off], *(const short*)&h[off1]);
    *(unsigned*)(lds + l*256 + ((2*(64 + c0)) ^ ((l & 7) << 4))) =
        pks(*(const short*)&hA[off], *(const short*)&hA[off1]);
  }
  __syncthreads();

  f32x4 acc[4];
#pragma unroll
  for (int i = 0; i < 4; i++) acc[i] = (f32x4){0.f, 0.f, 0.f, 0.f};
#pragma unroll
  for (int kk = 0; kk < 4; kk++) {
    short8v af = *(const short8v*)(dcwP + (size_t)(((kk*4 + mi)*64 + l) * 8));
    const int c0 = kk*32 + (l >> 4)*8;
#pragma unroll
    for (int ni = 0; ni < 4; ni++) {
      int tr = ni*16 + (l & 15);
      short8v bf = *(const short8v*)(lds + tr*256 + ((2*c0) ^ ((tr & 7) << 4)));
      acc[ni] = __builtin_amdgcn_mfma_f32_16x16x32_bf16(af, bf, acc[ni], 0, 0, 0);
    }
  }

  const int o0 = mi*16 + ((l >> 4) << 2);
  float dcb4[4];
#pragma unroll
  for (int r = 0; r < 4; r++) dcb4[r] = dcb[o0 + r];
#pragma unroll
  for (int ni = 0; ni < 4; ni++) {
    int t = ni*16 + (l & 15);
#pragma unroll
    for (int r = 0; r < 4; r++) {
      const int o = o0 + r;
      float hres = shortbf(*(const short*)(lds + t*256 + ((2*o) ^ ((t & 7) << 4))));
      float v = acc[ni][r] + hres + dcb4[r];
      size_t oidx = (((size_t)b * 64 + o) * NNODE + n) * TT + t0 + t;
      if (epi == 1) {
        outo[oidx] = x[(((size_t)b * 64 + o) * NNODE + n) * 512 + 2*(t0 + t) + 1] * tanhfast(v);
      } else if (epi == 2) {
        oute[oidx] = x[(((size_t)b * 64 + o) * NNODE + n) * 512 + 2*(t0 + t)] * tanhfast(v);
      } else if (epi == 3) {
        outo[oidx] -= v;
      } else {
        oute[oidx] += v;
      }
    }
  }
}

// ---------------- channel mix (b==7): exact fp32 ----------------
__global__ __launch_bounds__(256) void k_mix7(const float* __restrict__ h7f, const float* __restrict__ hA7f,
                                              const float* __restrict__ dcw, const float* __restrict__ dcb,
                                              const float* __restrict__ x,
                                              float* __restrict__ oute, float* __restrict__ outo, int epi) {
  const int n = blockIdx.x, tq = blockIdx.y;
  const int tid = threadIdx.x;
  const int lane = tid & 63;
  const int w = __builtin_amdgcn_readfirstlane(tid >> 6);
  const int t = tq * 64 + lane;
  __shared__ float wTs[128][64];
  __shared__ float hsf[64][64];
  __shared__ float hasf[64][64];
  for (int i = tid; i < 8192; i += 256) {
    int o_ = i & 63, cf_ = i >> 6;
    wTs[cf_][o_] = dcw[o_*128 + cf_];
  }
  for (int i = tid; i < 4096; i += 256) {
    int c = i >> 6, tl = i & 63;
    size_t off = ((size_t)c * NNODE + n) * TT + tq * 64 + tl;
    hsf[c][tl] = h7f[off];
    hasf[c][tl] = hA7f[off];
  }
  __syncthreads();
  const int o0 = w * 16;
  float acc[16];
#pragma unroll
  for (int oo = 0; oo < 16; oo++) acc[oo] = 0.f;
  for (int cc = 0; cc < 64; cc++) {
    float hv = hsf[cc][lane];
    float hav = hasf[cc][lane];
    float4 wh0 = *(const float4*)&wTs[cc][o0 + 0];
    float4 wh1 = *(const float4*)&wTs[cc][o0 + 4];
    float4 wh2 = *(const float4*)&wTs[cc][o0 + 8];
    float4 wh3 = *(const float4*)&wTs[cc][o0 + 12];
    float4 wa0 = *(const float4*)&wTs[64 + cc][o0 + 0];
    float4 wa1 = *(const float4*)&wTs[64 + cc][o0 + 4];
    float4 wa2 = *(const float4*)&wTs[64 + cc][o0 + 8];
    float4 wa3 = *(const float4*)&wTs[64 + cc][o0 + 12];
    acc[0]  += wh0.x*hv + wa0.x*hav;  acc[1]  += wh0.y*hv + wa0.y*hav;
    acc[2]  += wh0.z*hv + wa0.z*hav;  acc[3]  += wh0.w*hv + wa0.w*hav;
    acc[4]  += wh1.x*hv + wa1.x*hav;  acc[5]  += wh1.y*hv + wa1.y*hav;
    acc[6]  += wh1.z*hv + wa1.z*hav;  acc[7]  += wh1.w*hv + wa1.w*hav;
    acc[8]  += wh2.x*hv + wa2.x*hav;  acc[9]  += wh2.y*hv + wa2.y*hav;
    acc[10] += wh2.z*hv + wa2.z*hav;  acc[11] += wh2.w*hv + wa2.w*hav;
    acc[12] += wh3.x*hv + wa3.x*hav;  acc[13] += wh3.y*hv + wa3.y*hav;
    acc[14] += wh3.z*hv + wa3.z*hav;  acc[15] += wh3.w*hv + wa3.w*hav;
  }
#pragma unroll
  for (int oo = 0; oo < 16; oo++) {
    const int o = o0 + oo;
    float v = acc[oo] + hsf[o][lane] + dcb[o];
    size_t oidx = (((size_t)7 * 64 + o) * NNODE + n) * TT + t;
    if (epi == 1) {
      outo[oidx] = x[(((size_t)7 * 64 + o) * NNODE + n) * 512 + 2*t + 1] * tanhf(v);
    } else if (epi == 2) {
      oute[oidx] = x[(((size_t)7 * 64 + o) * NNODE + n) * 512 + 2*t] * tanhf(v);
    } else if (epi == 3) {
      outo[oidx] -= v;
    } else {
      oute[oidx] += v;
    }
  }
}

// ---------------- host ----------------
extern "C" void kernel_launch(void* const* d_in, const int* in_sizes, int n_in,
                              void* d_out, int out_size, void* d_ws, size_t ws_size,
                              hipStream_t stream) {
  const float* x    = (const float*)d_in[0];
  const float* nv1  = (const float*)d_in[1];
  const float* nv2  = (const float*)d_in[2];
  const float* a_in = (const float*)d_in[3];
  const float *w5[4], *b5[4], *w3[4], *b3[4];
  for (int s = 0; s < 4; s++) {
    w5[s] = (const float*)d_in[4 + 4*s];
    b5[s] = (const float*)d_in[5 + 4*s];
    w3[s] = (const float*)d_in[6 + 4*s];
    b3[s] = (const float*)d_in[7 + 4*s];
  }
  const float* ggw  = (const float*)d_in[20];
  const float* ggb  = (const float*)d_in[21];
  const float* fc0w = (const float*)d_in[22];
  const float* fc0b = (const float*)d_in[23];
  const float* fc1w = (const float*)d_in[24];
  const float* fc1b = (const float*)d_in[25];
  const float* fc2w = (const float*)d_in[26];
  const float* fc2b = (const float*)d_in[27];
  const float* dcw  = (const float*)d_in[28];
  const float* dcb  = (const float*)d_in[29];

  char* p = (char*)d_ws;
  size_t used = 0;
  auto alloc = [&](size_t bytes) -> char* {
    char* r = p + used;
    used += (bytes + 255) & ~(size_t)255;
    return r;
  };
  float* adjW   = (float*)alloc(GN*4);
  float* dadjW  = (float*)alloc(GN*4);
  float* gW     = (float*)alloc(4*GN*4);
  unsigned* keys= (unsigned*)alloc(8*4);
  float* STa    = (float*)alloc(CCH*NNODE*4);
  float* STb    = (float*)alloc(CCH*NNODE*4);
  float* Spart  = (float*)alloc(4*CCH*NNODE*4);
  float* H0     = (float*)alloc(NNODE*CCH*4);
  float* wT5[4]; float* wT3[4];
  short* wp5[4]; short* wp3[4];
  for (int s = 0; s < 4; s++) {
    wT5[s] = (float*)alloc(64*64*5*4);
    wT3[s] = (float*)alloc(64*64*3*4);
    wp5[s] = (short*)alloc(20480*2);
    wp3[s] = (short*)alloc(12288*2);
  }
  short* dcwP   = (short*)alloc(8192*2);
  short* dadjP  = (short*)alloc(33792*2);
  bf16* H1      = (bf16*)alloc(HSZ*2);
  bf16* H2      = (bf16*)alloc(HSZ*2);
  bf16* HA      = (bf16*)alloc(HSZ*2);
  float* h7fA   = (float*)alloc(H7SZ*4);
  float* h7fB   = (float*)alloc(H7SZ*4);
  float* hA7f   = (float*)alloc(H7SZ*4);
  if (used > ws_size) return;  // signature: output stays zero

  float* oute = (float*)d_out;
  float* outo = oute + HSZ;
  float* tail = oute + 2*HSZ;

  dim3 bgrid(NNODE, 4, 7);
  dim3 b7grid(NNODE, 4);
  dim3 agrid(448, 4);
  dim3 a7grid(64, 8);
  dim3 mgrid(NNODE, 7, 4);
  dim3 m7grid(NNODE, 4);

  for (int s = 0; s < 4; s++) {
    k_rep5T<<<80, 256, 0, stream>>>(w5[s], wT5[s]);
    k_rep3T<<<48, 256, 0, stream>>>(w3[s], wT3[s]);
    k_pack5<<<80, 256, 0, stream>>>(w5[s], wp5[s]);
    k_pack3<<<48, 256, 0, stream>>>(w3[s], wp3[s]);
  }
  k_packM<<<32, 256, 0, stream>>>(dcw, dcwP);
  k_adj<<<NNODE, 256, 0, stream>>>(nv1, nv2, adjW);
  k_keys<<<1, 64, 0, stream>>>(keys);
  k_gumbel<<<(4*GN + 255)/256, 256, 0, stream>>>(keys, gW);

  auto branch_all = [&](const float* src, int par, int s, bf16* Hb, float* h7f) {
    k_branchM<<<bgrid, 256, 0, stream>>>(src, par, b5[s], b3[s], wp5[s], wp3[s], Hb);
    k_branch7<<<b7grid, 256, 0, stream>>>(src, par, wT5[s], b5[s], wT3[s], b3[s], h7f, Spart);
  };
  auto graph_pipe = [&](float* ST, const float* gstep, float* tailp) {
    k_sredT<<<43, 256, 0, stream>>>(Spart, ST);
    k_s1h0<<<NNODE, 64, 0, stream>>>(ST, adjW, ggw, ggb, H0);
    k_fc<<<NNODE, 256, 0, stream>>>(H0, fc0w, fc0b, fc1w, fc1b, fc2w, fc2b,
                                    gstep, adjW, a_in, dadjW, tailp);
    k_packD<<<132, 256, 0, stream>>>(dadjW, dadjP);
  };
  auto hA_all = [&](bf16* Hb, float* h7f) {
    k_hA_m<<<agrid, 256, 0, stream>>>(Hb, dadjP, HA);
    k_hA7<<<a7grid, 256, 0, stream>>>(h7f, dadjW, hA7f);
  };
  auto mix_all = [&](bf16* Hb, float* h7f, int epi) {
    k_mix_m<<<mgrid, 256, 0, stream>>>(Hb, HA, dcwP, dcb, x, oute, outo, epi);
    k_mix7<<<m7grid, 256, 0, stream>>>(h7f, hA7f, dcw, dcb, x, oute, outo, epi);
  };

  // step 1: branch(xe) -> x1 ; d = xo*tanh(x1) -> outo
  branch_all(x, 0, 0, H1, h7fA);
  graph_pipe(STa, gW, nullptr);
  hA_all(H1, h7fA);
  mix_all(H1, h7fA, 1);

  // step 2: branch(xo) -> x2 ; c = xe*tanh(x2) -> oute
  branch_all(x, 1, 1, H1, h7fA);
  graph_pipe(STa, gW + GN, nullptr);
  hA_all(H1, h7fA);
  mix_all(H1, h7fA, 2);

  // steps 3 & 4: run both branches BEFORE either epilogue overwrites d_out
  branch_all(oute, -1, 2, H1, h7fA);
  k_sredT<<<43, 256, 0, stream>>>(Spart, STa);
  branch_all(outo, -1, 3, H2, h7fB);
  k_sredT<<<43, 256, 0, stream>>>(Spart, STb);

  // step 3 rest: outo = d - x3
  k_s1h0<<<NNODE, 64, 0, stream>>>(STa, adjW, ggw, ggb, H0);
  k_fc<<<NNODE, 256, 0, stream>>>(H0, fc0w, fc0b, fc1w, fc1b, fc2w, fc2b,
                                  gW + 2*GN, adjW, a_in, dadjW, nullptr);
  k_packD<<<132, 256, 0, stream>>>(dadjW, dadjP);
  hA_all(H1, h7fA);
  mix_all(H1, h7fA, 3);

  // step 4 rest: oute = c + x4 ; dadj -> tail
  k_s1h0<<<NNODE, 64, 0, stream>>>(STb, adjW, ggw, ggb, H0);
  k_fc<<<NNODE, 256, 0, stream>>>(H0, fc0w, fc0b, fc1w, fc1b, fc2w, fc2b,
                                  gW + 3*GN, adjW, a_in, dadjW, tail);
  k_packD<<<132, 256, 0, stream>>>(dadjW, dadjP);
  hA_all(H2, h7fB);
  mix_all(H2, h7fB, 4);

  (void)in_sizes; (void)n_in; (void)out_size;
}

// Round 12
// 1458.492 us; speedup vs baseline: 1.0442x; 1.0442x over previous
//
#include <hip/hip_runtime.h>
#include <hip/hip_bf16.h>
#include <cstdint>
#include <cstddef>

using bf16 = __hip_bfloat16;

static constexpr int BBATCH = 8, CCH = 64, NNODE = 170, TT = 256;
static constexpr size_t HSZ  = (size_t)BBATCH * CCH * NNODE * TT;  // 22282240
static constexpr size_t H7SZ = (size_t)CCH * NNODE * TT;           // 2785280
static constexpr int GN = NNODE * NNODE;                           // 28900

typedef __attribute__((ext_vector_type(8))) short short8v;
typedef __attribute__((ext_vector_type(4))) float f32x4;

__device__ __forceinline__ float b2f(bf16 v) { return __bfloat162float(v); }
__device__ __forceinline__ bf16  f2b(float v) { return __float2bfloat16(v); }

union BfU { bf16 h; unsigned short s; };
__device__ __forceinline__ unsigned short bfbits(float v) { BfU u; u.h = f2b(v); return u.s; }
__device__ __forceinline__ unsigned pack2(float a, float b) {
  return ((unsigned)bfbits(b) << 16) | bfbits(a);
}
__device__ __forceinline__ unsigned pks(short lo, short hi) {
  return ((unsigned)(unsigned short)hi << 16) | (unsigned short)lo;
}
__device__ __forceinline__ float shortbf(short s) { BfU u; u.s = (unsigned short)s; return b2f(u.h); }

// fast tanh for the VALUE path only (b<7): ~1e-6 rel err, correct saturation.
__device__ __forceinline__ float tanhfast(float v) {
  float e = __expf(2.f * v);
  return 1.f - 2.f / (e + 1.f);
}

// ---------------- threefry2x32 (JAX-compatible, partitionable) ----------------
__device__ __forceinline__ unsigned rotl32(unsigned v, int d) { return (v << d) | (v >> (32 - d)); }

__device__ void threefry2x32(unsigned k0, unsigned k1, unsigned x0, unsigned x1,
                             unsigned& y0, unsigned& y1) {
  unsigned ks0 = k0, ks1 = k1, ks2 = k0 ^ k1 ^ 0x1BD11BDAu;
  x0 += ks0; x1 += ks1;
  const int ra[4] = {13, 15, 26, 6};
  const int rb[4] = {17, 29, 16, 24};
#pragma unroll
  for (int r = 0; r < 4; r++) { x0 += x1; x1 = rotl32(x1, ra[r]); x1 ^= x0; }
  x0 += ks1; x1 += ks2 + 1u;
#pragma unroll
  for (int r = 0; r < 4; r++) { x0 += x1; x1 = rotl32(x1, rb[r]); x1 ^= x0; }
  x0 += ks2; x1 += ks0 + 2u;
#pragma unroll
  for (int r = 0; r < 4; r++) { x0 += x1; x1 = rotl32(x1, ra[r]); x1 ^= x0; }
  x0 += ks0; x1 += ks1 + 3u;
#pragma unroll
  for (int r = 0; r < 4; r++) { x0 += x1; x1 = rotl32(x1, rb[r]); x1 ^= x0; }
  x0 += ks1; x1 += ks2 + 4u;
#pragma unroll
  for (int r = 0; r < 4; r++) { x0 += x1; x1 = rotl32(x1, ra[r]); x1 ^= x0; }
  x0 += ks2; x1 += ks0 + 5u;
  y0 = x0; y1 = x1;
}

// ---------------- mega setup kernel: adj + gumbel + all weight packs ----------------
struct SetupArgs {
  const float* w5[4]; const float* w3[4];
  float* wT5[4]; float* wT3[4];
  short* wp5[4]; short* wp3[4];
  const float* dcw; short* dcwP;
  const float* nv1; const float* nv2; float* adj;
  float* g;
};

__global__ __launch_bounds__(256) void k_setup(SetupArgs a) {
  const int blk = blockIdx.x;
  const int tid = threadIdx.x;
  __shared__ float red[256];

  if (blk < 170) {
    // adj = softmax(relu(nv1@nv2), axis=1), block = row i
    const int i = blk, j = tid;
    float val = 0.f, r = -1e30f;
    if (j < NNODE) {
      float acc = 0.f;
      for (int k = 0; k < 10; k++) acc += a.nv1[i*10+k] * a.nv2[k*NNODE+j];
      val = acc > 0.f ? acc : 0.f;
      r = val;
    }
    red[j] = r; __syncthreads();
    for (int s = 128; s; s >>= 1) { if (j < s) red[j] = fmaxf(red[j], red[j+s]); __syncthreads(); }
    float m = red[0]; __syncthreads();
    float e = (j < NNODE) ? expf(val - m) : 0.f;
    red[j] = e; __syncthreads();
    for (int s = 128; s; s >>= 1) { if (j < s) red[j] += red[j+s]; __syncthreads(); }
    if (j < NNODE) a.adj[i*NNODE+j] = e / red[0];
    return;
  }
  if (blk < 622) {
    // gumbel with inline fold-key: key_w = threefry(0,42, 0,w); bits = y0^y1 of threefry(key_w, 0, i)
    int idx = (blk - 170) * 256 + tid;
    if (idx >= 4 * GN) return;
    int w = idx / GN, i = idx % GN;
    unsigned k0, k1, y0, y1;
    threefry2x32(0u, 42u, 0u, (unsigned)w, k0, k1);
    threefry2x32(k0, k1, 0u, (unsigned)i, y0, y1);
    unsigned bits = y0 ^ y1;
    unsigned fb = (bits >> 9) | 0x3f800000u;
    float u = __uint_as_float(fb) - 1.0f;
    a.g[idx] = -logf(-logf(u + 1e-20f) + 1e-20f);
    return;
  }
  if (blk < 942) {
    // rep5T: w5 (o,c,5) -> wT5 (c,k,o)
    int gi = blk - 622, s = gi / 80;
    int idx = (gi - s*80) * 256 + tid;
    if (idx >= 20480) return;
    int oc = idx / 5, k = idx - oc * 5;
    int o = oc >> 6, c = oc & 63;
    a.wT5[s][(c*5 + k)*64 + o] = a.w5[s][idx];
    return;
  }
  if (blk < 1134) {
    // rep3T
    int gi = blk - 942, s = gi / 48;
    int idx = (gi - s*48) * 256 + tid;
    if (idx >= 12288) return;
    int oc = idx / 3, k = idx - oc * 3;
    int o = oc >> 6, c = oc & 63;
    a.wT3[s][(c*3 + k)*64 + o] = a.w3[s][idx];
    return;
  }
  if (blk < 1454) {
    // pack5 A-fragments
    int gi = blk - 1134, s = gi / 80;
    int idx = (gi - s*80) * 256 + tid;
    if (idx >= 20480) return;
    int j = idx & 7, l = (idx >> 3) & 63, mi = (idx >> 9) & 3, ks = (idx >> 11) & 1, k = idx >> 12;
    int o = mi*16 + (l & 15);
    int c = ks*32 + (l >> 4)*8 + j;
    a.wp5[s][idx] = (short)bfbits(a.w5[s][(o*64 + c)*5 + k]);
    return;
  }
  if (blk < 1646) {
    // pack3
    int gi = blk - 1454, s = gi / 48;
    int idx = (gi - s*48) * 256 + tid;
    if (idx >= 12288) return;
    int j = idx & 7, l = (idx >> 3) & 63, mi = (idx >> 9) & 3, ks = (idx >> 11) & 1, k = idx >> 12;
    int o = mi*16 + (l & 15);
    int c = ks*32 + (l >> 4)*8 + j;
    a.wp3[s][idx] = (short)bfbits(a.w3[s][(o*64 + c)*3 + k]);
    return;
  }
  {
    // packM: dcw (o,128) -> A-fragments
    int idx = (blk - 1646) * 256 + tid;
    if (idx >= 8192) return;
    int j = idx & 7, l = (idx >> 3) & 63, mi = (idx >> 9) & 3, kk = idx >> 11;
    int o = mi*16 + (l & 15);
    int c = kk*32 + (l >> 4)*8 + j;
    a.dcwP[idx] = (short)bfbits(a.dcw[o*128 + c]);
  }
}

// dadj^T -> A-fragments: A[m][n] = dadj[n][m]; 11 m-tiles x 6 k-steps, zero-padded
__global__ __launch_bounds__(256) void k_packD(const float* __restrict__ dadj, short* __restrict__ out) {
  int idx = blockIdx.x * 256 + threadIdx.x;
  if (idx >= 33792) return;
  int j = idx & 7, l = (idx >> 3) & 63;
  int g = idx >> 9;
  int ks = g % 6, mi = g / 6;
  int m = mi*16 + (l & 15);
  int n = ks*32 + (l >> 4)*8 + j;
  float v = (m < NNODE && n < NNODE) ? dadj[n*NNODE + m] : 0.f;
  out[idx] = (short)bfbits(v);
}

// ---------------- fused branch: conv5(edgepad)+leaky + conv3 + tanh (R10 version) ----------------
__global__ __launch_bounds__(256) void k_branch(
    const float* __restrict__ src, int par,
    const float* __restrict__ wT5, const float* __restrict__ b5,
    const float* __restrict__ wT3, const float* __restrict__ b3,
    const short* __restrict__ wp5, const short* __restrict__ wp3,
    bf16* __restrict__ hout, float* __restrict__ h7f, float* __restrict__ Spart) {
  const int n = blockIdx.x, q = blockIdx.y, b = blockIdx.z;
  const int tid = threadIdx.x;
  const int l = tid & 63;
  const int w = __builtin_amdgcn_readfirstlane(tid >> 6);
  const int t0 = q * 64;
  __shared__ char lds[35840];

  if (b == 7) {
    // ================= fp32 exact path (argmax chain) =================
    float (*xs)[72]  = (float(*)[72])lds;
    float (*h1s)[68] = (float(*)[68])(lds + 18432);
    const int o = l;
    const int base = w * 16;
    const bool w3x = (w == 3);

    for (int i = tid; i < 64 * 70; i += 256) {
      int c = i / 70, pl = i - c * 70;
      int t = t0 + pl - 3; t = t < 0 ? 0 : (t > 255 ? 255 : t);
      size_t sb = ((size_t)7 * 64 + c) * NNODE + n;
      xs[c][pl] = (par >= 0) ? src[sb * 512 + 2 * t + par] : src[sb * 256 + t];
    }
    __syncthreads();

    {
      float acc[16];
#pragma unroll
      for (int tt = 0; tt < 16; tt++) acc[tt] = 0.f;
      float aH0 = 0.f, aH1 = 0.f;
      const float* wp = wT5 + o;
      for (int c = 0; c < 64; c++) {
        float xv[22];
        float4 v0 = *(const float4*)&xs[c][base + 0];
        float4 v1 = *(const float4*)&xs[c][base + 4];
        float4 v2 = *(const float4*)&xs[c][base + 8];
        float4 v3 = *(const float4*)&xs[c][base + 12];
        float4 v4 = *(const float4*)&xs[c][base + 16];
        xv[0]=v0.x; xv[1]=v0.y; xv[2]=v0.z; xv[3]=v0.w;
        xv[4]=v1.x; xv[5]=v1.y; xv[6]=v1.z; xv[7]=v1.w;
        xv[8]=v2.x; xv[9]=v2.y; xv[10]=v2.z; xv[11]=v2.w;
        xv[12]=v3.x; xv[13]=v3.y; xv[14]=v3.z; xv[15]=v3.w;
        xv[16]=v4.x; xv[17]=v4.y; xv[18]=v4.z; xv[19]=v4.w;
        if (w3x) { float2 vt = *(const float2*)&xs[c][68]; xv[20]=vt.x; xv[21]=vt.y; }
        float w0 = wp[0], w1 = wp[64], w2 = wp[128], w3_ = wp[192], w4 = wp[256];
        wp += 320;
#pragma unroll
        for (int tt = 0; tt < 16; tt++)
          acc[tt] += w0*xv[tt] + w1*xv[tt+1] + w2*xv[tt+2] + w3_*xv[tt+3] + w4*xv[tt+4];
        if (w3x) {
          aH0 += w0*xv[16] + w1*xv[17] + w2*xv[18] + w3_*xv[19] + w4*xv[20];
          aH1 += w0*xv[17] + w1*xv[18] + w2*xv[19] + w3_*xv[20] + w4*xv[21];
        }
      }
      float bias = b5[o];
#pragma unroll
      for (int tt = 0; tt < 16; tt++) {
        float v = acc[tt] + bias;
        h1s[o][base + tt] = v >= 0.f ? v : 0.01f * v;
      }
      if (w3x) {
        float u0 = aH0 + bias, u1 = aH1 + bias;
        h1s[o][64] = u0 >= 0.f ? u0 : 0.01f * u0;
        h1s[o][65] = u1 >= 0.f ? u1 : 0.01f * u1;
      }
    }
    __syncthreads();

    {
      float acc[16];
#pragma unroll
      for (int tt = 0; tt < 16; tt++) acc[tt] = 0.f;
      const float* wp = wT3 + o;
      for (int c = 0; c < 64; c++) {
        float hv[18];
        float4 v0 = *(const float4*)&h1s[c][base + 0];
        float4 v1 = *(const float4*)&h1s[c][base + 4];
        float4 v2 = *(const float4*)&h1s[c][base + 8];
        float4 v3 = *(const float4*)&h1s[c][base + 12];
        float4 v4 = *(const float4*)&h1s[c][base + 16];
        hv[0]=v0.x; hv[1]=v0.y; hv[2]=v0.z; hv[3]=v0.w;
        hv[4]=v1.x; hv[5]=v1.y; hv[6]=v1.z; hv[7]=v1.w;
        hv[8]=v2.x; hv[9]=v2.y; hv[10]=v2.z; hv[11]=v2.w;
        hv[12]=v3.x; hv[13]=v3.y; hv[14]=v3.z; hv[15]=v3.w;
        hv[16]=v4.x; hv[17]=v4.y;
        float w0 = wp[0], w1 = wp[64], w2 = wp[128];
        wp += 192;
#pragma unroll
        for (int tt = 0; tt < 16; tt++)
          acc[tt] += w0*hv[tt] + w1*hv[tt+1] + w2*hv[tt+2];
      }
      float bias = b3[o];
#pragma unroll
      for (int tt = 0; tt < 16; tt++) acc[tt] = tanhf(acc[tt] + bias);
      __syncthreads();
#pragma unroll
      for (int tt = 0; tt < 16; tt++) xs[o][base + tt] = acc[tt];
    }
    __syncthreads();

    {
      const int ro = tid >> 2, rq = tid & 3;
      float4 v0 = *(const float4*)&xs[ro][rq*16 + 0];
      float4 v1 = *(const float4*)&xs[ro][rq*16 + 4];
      float4 v2 = *(const float4*)&xs[ro][rq*16 + 8];
      float4 v3 = *(const float4*)&xs[ro][rq*16 + 12];
      float* dst = h7f + ((size_t)ro * NNODE + n) * TT + t0 + rq*16;
      *(float4*)&dst[0] = v0; *(float4*)&dst[4] = v1;
      *(float4*)&dst[8] = v2; *(float4*)&dst[12] = v3;
      float s = v0.x+v0.y+v0.z+v0.w + v1.x+v1.y+v1.z+v1.w
              + v2.x+v2.y+v2.z+v2.w + v3.x+v3.y+v3.z+v3.w;
      s += __shfl_xor(s, 1, 4);
      s += __shfl_xor(s, 2, 4);
      if (rq == 0) Spart[(q * 64 + ro) * NNODE + n] = s;
    }
    return;
  }

  // ================= bf16 MFMA path (b < 7) =================
  const int mi = w;

  for (int it = 0; it < 16; it++) {
    int c = it * 4 + w;
    int t = t0 + l - 3; t = t < 0 ? 0 : (t > 255 ? 255 : t);
    size_t sb = ((size_t)b * 64 + c) * NNODE + n;
    float v = (par >= 0) ? src[sb * 512 + 2 * t + par] : src[sb * 256 + t];
    *(short*)(lds + l*128 + ((2*c) ^ ((l & 7) << 4))) = (short)bfbits(v);
  }
  for (int i = tid; i < 6 * 64; i += 256) {
    int tr = 64 + (i >> 6);
    int c = i & 63;
    int t = t0 + tr - 3; if (t > 255) t = 255;
    size_t sb = ((size_t)b * 64 + c) * NNODE + n;
    float v = (par >= 0) ? src[sb * 512 + 2 * t + par] : src[sb * 256 + t];
    *(short*)(lds + tr*128 + ((2*c) ^ ((tr & 7) << 4))) = (short)bfbits(v);
  }
  __syncthreads();

  f32x4 acc[5];
#pragma unroll
  for (int i = 0; i < 5; i++) acc[i] = (f32x4){0.f, 0.f, 0.f, 0.f};
  for (int k = 0; k < 5; k++) {
#pragma unroll
    for (int ks = 0; ks < 2; ks++) {
      short8v af = *(const short8v*)(wp5 + (size_t)((((k*2 + ks)*4 + mi)*64 + l) * 8));
      const int c0 = ks*32 + (l >> 4)*8;
#pragma unroll
      for (int ni = 0; ni < 5; ni++) {
        int tr = ni*16 + (l & 15) + k;
        short8v bf = *(const short8v*)(lds + tr*128 + ((2*c0) ^ ((tr & 7) << 4)));
        acc[ni] = __builtin_amdgcn_mfma_f32_16x16x32_bf16(af, bf, acc[ni], 0, 0, 0);
      }
    }
  }
  {
    const int o0 = mi*16 + ((l >> 4) << 2);
    float4 bv = *(const float4*)&b5[o0];
    float bb[4] = {bv.x, bv.y, bv.z, bv.w};
#pragma unroll
    for (int ni = 0; ni < 4; ni++) {
      int tr = ni*16 + (l & 15);
      float v[4];
#pragma unroll
      for (int r = 0; r < 4; r++) {
        float u = acc[ni][r] + bb[r];
        v[r] = u >= 0.f ? u : 0.01f * u;
      }
      int colb = (2*o0) ^ ((tr & 7) << 4);
      *(uint2*)(lds + 10752 + tr*128 + colb) = make_uint2(pack2(v[0], v[1]), pack2(v[2], v[3]));
    }
    if ((l & 15) < 2) {
      int tr = 64 + (l & 15);
      float v[4];
#pragma unroll
      for (int r = 0; r < 4; r++) {
        float u = acc[4][r] + bb[r];
        v[r] = u >= 0.f ? u : 0.01f * u;
      }
      int colb = (2*o0) ^ ((tr & 7) << 4);
      *(uint2*)(lds + 10752 + tr*128 + colb) = make_uint2(pack2(v[0], v[1]), pack2(v[2], v[3]));
    }
  }
  __syncthreads();

  f32x4 acc3[4];
#pragma unroll
  for (int i = 0; i < 4; i++) acc3[i] = (f32x4){0.f, 0.f, 0.f, 0.f};
  for (int k = 0; k < 3; k++) {
#pragma unroll
    for (int ks = 0; ks < 2; ks++) {
      short8v af = *(const short8v*)(wp3 + (size_t)((((k*2 + ks)*4 + mi)*64 + l) * 8));
      const int c0 = ks*32 + (l >> 4)*8;
#pragma unroll
      for (int ni = 0; ni < 4; ni++) {
        int tr = ni*16 + (l & 15) + k;
        short8v bf = *(const short8v*)(lds + 10752 + tr*128 + ((2*c0) ^ ((tr & 7) << 4)));
        acc3[ni] = __builtin_amdgcn_mfma_f32_16x16x32_bf16(af, bf, acc3[ni], 0, 0, 0);
      }
    }
  }
  {
    const int o0 = mi*16 + ((l >> 4) << 2);
    float4 bv = *(const float4*)&b3[o0];
    float bb[4] = {bv.x, bv.y, bv.z, bv.w};
#pragma unroll
    for (int ni = 0; ni < 4; ni++) {
      int t = ni*16 + (l & 15);
#pragma unroll
      for (int r = 0; r < 4; r++) {
        float v = tanhfast(acc3[ni][r] + bb[r]);
        *(short*)(lds + (o0 + r)*144 + t*2) = (short)bfbits(v);
      }
    }
  }
  __syncthreads();

  {
    const int ro = tid >> 2, rq = tid & 3;
    uint4 p0 = *(const uint4*)(lds + ro*144 + rq*32);
    uint4 p1 = *(const uint4*)(lds + ro*144 + rq*32 + 16);
    bf16* dst = hout + (((size_t)b * 64 + ro) * NNODE + n) * TT + t0 + rq*16;
    *(uint4*)&dst[0] = p0;
    *(uint4*)&dst[8] = p1;
  }
}

// ---------------- ST[n][c] = sum_q Spart ----------------
__global__ __launch_bounds__(256) void k_sredT(const float* __restrict__ Spart, float* __restrict__ ST) {
  int idx = blockIdx.x * 256 + threadIdx.x;
  if (idx >= CCH * NNODE) return;
  int nn = idx >> 6, c = idx & 63;
  float acc = 0.f;
#pragma unroll
  for (int qq = 0; qq < 4; qq++) acc += Spart[(qq * 64 + c) * NNODE + nn];
  ST[idx] = acc;
}

// ---------------- fused S1+H0+fc0+fc1+fc2+gumbel-argmax+dadj (block per node i) ----------------
__global__ __launch_bounds__(256) void k_gg(const float* __restrict__ ST, const float* __restrict__ adj,
    const float* __restrict__ ggw, const float* __restrict__ ggb,
    const float* __restrict__ fc0w, const float* __restrict__ fc0b,
    const float* __restrict__ fc1w, const float* __restrict__ fc1b,
    const float* __restrict__ fc2w, const float* __restrict__ fc2b,
    const float* __restrict__ g, const float* __restrict__ a_in,
    float* __restrict__ dadj, float* __restrict__ out_tail) {
  const int i = blockIdx.x;
  const int tid = threadIdx.x;
  __shared__ float s1[64], sc[64], h0r[64];
  __shared__ float a1r[NNODE];
  __shared__ float a2r[340];
  __shared__ float vred[256];
  __shared__ int ired[256];
  if (tid < 64) {
    const int c = tid;
    float acc = 0.f;
    for (int nn = 0; nn < NNODE; nn++) acc += ST[nn*64 + c] * adj[nn*NNODE + i];
    s1[c] = acc;
    sc[c] = ST[i*64 + c];
  }
  __syncthreads();
  if (tid < 64) {
    const int o = tid;
    float acc = 256.f * ggb[o];
    for (int c = 0; c < 64; c++)
      acc += ggw[o*128 + c] * sc[c] + ggw[o*128 + 64 + c] * s1[c];
    h0r[o] = acc;
  }
  __syncthreads();
  if (tid < NNODE) {
    float acc = fc0b[tid];
    for (int o = 0; o < 64; o++) acc += h0r[o] * fc0w[tid*64 + o];
    a1r[tid] = tanhf(acc);
  }
  __syncthreads();
  for (int j = tid; j < 340; j += 256) {
    float acc = fc1b[j];
    for (int k = 0; k < NNODE; k++) acc += a1r[k] * fc1w[j*NNODE + k];
    a2r[j] = tanhf(acc);
  }
  __syncthreads();
  float v = -1e30f;
  if (tid < NNODE) {
    float acc = fc2b[tid];
    for (int k = 0; k < 340; k++) acc += a2r[k] * fc2w[tid*340 + k];
    v = tanhf(acc) + g[i*NNODE + tid];
  }
  vred[tid] = v; ired[tid] = tid;
  __syncthreads();
  for (int s = 128; s; s >>= 1) {
    if (tid < s) {
      if (vred[tid+s] > vred[tid]) { vred[tid] = vred[tid+s]; ired[tid] = ired[tid+s]; }
    }
    __syncthreads();
  }
  int jmax = ired[0];
  float a = a_in[0];
  if (tid < NNODE) {
    float la = (tid == jmax && jmax != i) ? 1.f : 0.f;
    float dv = la * a + adj[i*NNODE + tid] * (1.f - a);
    dadj[i*NNODE + tid] = dv;
    if (out_tail) out_tail[i*NNODE + tid] = dv;
  }
}

// ---------------- hA (b<7) via MFMA ----------------
__global__ __launch_bounds__(256) void k_hA_m(const bf16* __restrict__ h, const short* __restrict__ dP,
                                              bf16* __restrict__ hA) {
  const int bc = blockIdx.x, tq = blockIdx.y;
  const int tid = threadIdx.x;
  const int l = tid & 63;
  const int w = __builtin_amdgcn_readfirstlane(tid >> 6);
  const int t0 = tq * 64;
  __shared__ char lds[25600];

  const bf16* hp = h + (size_t)bc * NNODE * TT;
  for (int i = tid; i < 170*64; i += 256) {
    int n = i >> 6, t = i & 63;
    *(short*)(lds + t*400 + ((2*n) ^ ((t & 7) << 4))) = *(const short*)&hp[(size_t)n * TT + t0 + t];
  }
  for (int i = tid; i < 22*64; i += 256) {
    int n = 170 + (i >> 6), t = i & 63;
    *(short*)(lds + t*400 + ((2*n) ^ ((t & 7) << 4))) = 0;
  }
  __syncthreads();

  f32x4 acc[11];
#pragma unroll
  for (int i = 0; i < 11; i++) acc[i] = (f32x4){0.f, 0.f, 0.f, 0.f};
  const int tr = w*16 + (l & 15);
#pragma unroll
  for (int ks = 0; ks < 6; ks++) {
    const int n0 = ks*32 + (l >> 4)*8;
    short8v bf = *(const short8v*)(lds + tr*400 + ((2*n0) ^ ((tr & 7) << 4)));
#pragma unroll
    for (int mi = 0; mi < 11; mi++) {
      short8v af = *(const short8v*)(dP + (size_t)(((mi*6 + ks)*64 + l) * 8));
      acc[mi] = __builtin_amdgcn_mfma_f32_16x16x32_bf16(af, bf, acc[mi], 0, 0, 0);
    }
  }

  bf16* dst = hA + (size_t)bc * NNODE * TT + t0 + w*16 + (l & 15);
#pragma unroll
  for (int mi = 0; mi < 11; mi++) {
#pragma unroll
    for (int r = 0; r < 4; r++) {
      int m = mi*16 + ((l >> 4) << 2) + r;
      if (m < NNODE) dst[(size_t)m * TT] = f2b(acc[mi][r]);
    }
  }
}

// ---------------- hA (b==7): exact fp32 path ----------------
__global__ __launch_bounds__(256) void k_hA7(const float* __restrict__ h7f,
                                             const float* __restrict__ dadj,
                                             float* __restrict__ hA7f) {
  const int c = blockIdx.x, tq = blockIdx.y;
  const int t0 = tq * 32;
  const int tid = threadIdx.x;
  const int lane = tid & 63;
  const int w = __builtin_amdgcn_readfirstlane(tid >> 6);
  __shared__ float hs[170][33];
  for (int i = tid; i < 170*32; i += 256) {
    int nn = i >> 5, tl = i & 31;
    hs[nn][tl] = h7f[((size_t)c * NNODE + nn) * TT + t0 + tl];
  }
  __syncthreads();
  float acc0[8], acc1[8], acc2[8];
#pragma unroll
  for (int tt = 0; tt < 8; tt++) { acc0[tt] = 0.f; acc1[tt] = 0.f; acc2[tt] = 0.f; }
  const int toff = w * 8;
  for (int nn = 0; nn < NNODE; nn++) {
    float hv[8];
#pragma unroll
    for (int tt = 0; tt < 8; tt++) hv[tt] = hs[nn][toff + tt];
    const float* dr = &dadj[nn * NNODE];
    float w0 = dr[lane];
    float w1 = dr[64 + lane];
    float w2 = (lane < 42) ? dr[128 + lane] : 0.f;
#pragma unroll
    for (int tt = 0; tt < 8; tt++) {
      acc0[tt] += w0 * hv[tt];
      acc1[tt] += w1 * hv[tt];
      acc2[tt] += w2 * hv[tt];
    }
  }
  __syncthreads();
#pragma unroll
  for (int tt = 0; tt < 8; tt++) {
    hs[lane][toff + tt] = acc0[tt];
    hs[64 + lane][toff + tt] = acc1[tt];
    if (lane < 42) hs[128 + lane][toff + tt] = acc2[tt];
  }
  __syncthreads();
  if (tid < NNODE) {
    float* dst = hA7f + ((size_t)c * NNODE + tid) * TT + t0;
#pragma unroll
    for (int j = 0; j < 8; j++)
      *(float4*)&dst[j*4] = make_float4(hs[tid][j*4], hs[tid][j*4+1], hs[tid][j*4+2], hs[tid][j*4+3]);
  }
}

// ---------------- channel mix (b<7): bf16 MFMA GEMM ----------------
__global__ __launch_bounds__(256) void k_mix_m(const bf16* __restrict__ h, const bf16* __restrict__ hA,
                                               const short* __restrict__ dcwP, const float* __restrict__ dcb,
                                               const float* __restrict__ x,
                                               float* __restrict__ oute, float* __restrict__ outo, int epi) {
  const int n = blockIdx.x, b = blockIdx.y, tq = blockIdx.z;
  const int tid = threadIdx.x;
  const int l = tid & 63;
  const int mi = __builtin_amdgcn_readfirstlane(tid >> 6);
  const int t0 = tq * 64;
  __shared__ char lds[16384];

#pragma unroll
  for (int it = 0; it < 8; it++) {
    int c0 = it * 8 + mi * 2;
    size_t off = (((size_t)b * 64 + c0) * NNODE + n) * TT + t0 + l;
    size_t off1 = off + (size_t)NNODE * TT;
    *(unsigned*)(lds + l*256 + ((2*c0) ^ ((l & 7) << 4))) =
        pks(*(const short*)&h[off], *(const short*)&h[off1]);
    *(unsigned*)(lds + l*256 + ((2*(64 + c0)) ^ ((l & 7) << 4))) =
        pks(*(const short*)&hA[off], *(const short*)&hA[off1]);
  }
  __syncthreads();

  f32x4 acc[4];
#pragma unroll
  for (int i = 0; i < 4; i++) acc[i] = (f32x4){0.f, 0.f, 0.f, 0.f};
#pragma unroll
  for (int kk = 0; kk < 4; kk++) {
    short8v af = *(const short8v*)(dcwP + (size_t)(((kk*4 + mi)*64 + l) * 8));
    const int c0 = kk*32 + (l >> 4)*8;
#pragma unroll
    for (int ni = 0; ni < 4; ni++) {
      int tr = ni*16 + (l & 15);
      short8v bf = *(const short8v*)(lds + tr*256 + ((2*c0) ^ ((tr & 7) << 4)));
      acc[ni] = __builtin_amdgcn_mfma_f32_16x16x32_bf16(af, bf, acc[ni], 0, 0, 0);
    }
  }

  const int o0 = mi*16 + ((l >> 4) << 2);
  float dcb4[4];
#pragma unroll
  for (int r = 0; r < 4; r++) dcb4[r] = dcb[o0 + r];
#pragma unroll
  for (int ni = 0; ni < 4; ni++) {
    int t = ni*16 + (l & 15);
#pragma unroll
    for (int r = 0; r < 4; r++) {
      const int o = o0 + r;
      float hres = shortbf(*(const short*)(lds + t*256 + ((2*o) ^ ((t & 7) << 4))));
      float v = acc[ni][r] + hres + dcb4[r];
      size_t oidx = (((size_t)b * 64 + o) * NNODE + n) * TT + t0 + t;
      if (epi == 1) {
        outo[oidx] = x[(((size_t)b * 64 + o) * NNODE + n) * 512 + 2*(t0 + t) + 1] * tanhfast(v);
      } else if (epi == 2) {
        oute[oidx] = x[(((size_t)b * 64 + o) * NNODE + n) * 512 + 2*(t0 + t)] * tanhfast(v);
      } else if (epi == 3) {
        outo[oidx] -= v;
      } else {
        oute[oidx] += v;
      }
    }
  }
}

// ---------------- channel mix (b==7): exact fp32 ----------------
__global__ __launch_bounds__(256) void k_mix7(const float* __restrict__ h7f, const float* __restrict__ hA7f,
                                              const float* __restrict__ dcw, const float* __restrict__ dcb,
                                              const float* __restrict__ x,
                                              float* __restrict__ oute, float* __restrict__ outo, int epi) {
  const int n = blockIdx.x, tq = blockIdx.y;
  const int tid = threadIdx.x;
  const int lane = tid & 63;
  const int w = __builtin_amdgcn_readfirstlane(tid >> 6);
  const int t = tq * 64 + lane;
  __shared__ float wTs[128][64];
  __shared__ float hsf[64][64];
  __shared__ float hasf[64][64];
  for (int i = tid; i < 8192; i += 256) {
    int o_ = i & 63, cf_ = i >> 6;
    wTs[cf_][o_] = dcw[o_*128 + cf_];
  }
  for (int i = tid; i < 4096; i += 256) {
    int c = i >> 6, tl = i & 63;
    size_t off = ((size_t)c * NNODE + n) * TT + tq * 64 + tl;
    hsf[c][tl] = h7f[off];
    hasf[c][tl] = hA7f[off];
  }
  __syncthreads();
  const int o0 = w * 16;
  float acc[16];
#pragma unroll
  for (int oo = 0; oo < 16; oo++) acc[oo] = 0.f;
  for (int cc = 0; cc < 64; cc++) {
    float hv = hsf[cc][lane];
    float hav = hasf[cc][lane];
    float4 wh0 = *(const float4*)&wTs[cc][o0 + 0];
    float4 wh1 = *(const float4*)&wTs[cc][o0 + 4];
    float4 wh2 = *(const float4*)&wTs[cc][o0 + 8];
    float4 wh3 = *(const float4*)&wTs[cc][o0 + 12];
    float4 wa0 = *(const float4*)&wTs[64 + cc][o0 + 0];
    float4 wa1 = *(const float4*)&wTs[64 + cc][o0 + 4];
    float4 wa2 = *(const float4*)&wTs[64 + cc][o0 + 8];
    float4 wa3 = *(const float4*)&wTs[64 + cc][o0 + 12];
    acc[0]  += wh0.x*hv + wa0.x*hav;  acc[1]  += wh0.y*hv + wa0.y*hav;
    acc[2]  += wh0.z*hv + wa0.z*hav;  acc[3]  += wh0.w*hv + wa0.w*hav;
    acc[4]  += wh1.x*hv + wa1.x*hav;  acc[5]  += wh1.y*hv + wa1.y*hav;
    acc[6]  += wh1.z*hv + wa1.z*hav;  acc[7]  += wh1.w*hv + wa1.w*hav;
    acc[8]  += wh2.x*hv + wa2.x*hav;  acc[9]  += wh2.y*hv + wa2.y*hav;
    acc[10] += wh2.z*hv + wa2.z*hav;  acc[11] += wh2.w*hv + wa2.w*hav;
    acc[12] += wh3.x*hv + wa3.x*hav;  acc[13] += wh3.y*hv + wa3.y*hav;
    acc[14] += wh3.z*hv + wa3.z*hav;  acc[15] += wh3.w*hv + wa3.w*hav;
  }
#pragma unroll
  for (int oo = 0; oo < 16; oo++) {
    const int o = o0 + oo;
    float v = acc[oo] + hsf[o][lane] + dcb[o];
    size_t oidx = (((size_t)7 * 64 + o) * NNODE + n) * TT + t;
    if (epi == 1) {
      outo[oidx] = x[(((size_t)7 * 64 + o) * NNODE + n) * 512 + 2*t + 1] * tanhf(v);
    } else if (epi == 2) {
      oute[oidx] = x[(((size_t)7 * 64 + o) * NNODE + n) * 512 + 2*t] * tanhf(v);
    } else if (epi == 3) {
      outo[oidx] -= v;
    } else {
      oute[oidx] += v;
    }
  }
}

// ---------------- host ----------------
extern "C" void kernel_launch(void* const* d_in, const int* in_sizes, int n_in,
                              void* d_out, int out_size, void* d_ws, size_t ws_size,
                              hipStream_t stream) {
  const float* x    = (const float*)d_in[0];
  const float* nv1  = (const float*)d_in[1];
  const float* nv2  = (const float*)d_in[2];
  const float* a_in = (const float*)d_in[3];
  const float *w5[4], *b5[4], *w3[4], *b3[4];
  for (int s = 0; s < 4; s++) {
    w5[s] = (const float*)d_in[4 + 4*s];
    b5[s] = (const float*)d_in[5 + 4*s];
    w3[s] = (const float*)d_in[6 + 4*s];
    b3[s] = (const float*)d_in[7 + 4*s];
  }
  const float* ggw  = (const float*)d_in[20];
  const float* ggb  = (const float*)d_in[21];
  const float* fc0w = (const float*)d_in[22];
  const float* fc0b = (const float*)d_in[23];
  const float* fc1w = (const float*)d_in[24];
  const float* fc1b = (const float*)d_in[25];
  const float* fc2w = (const float*)d_in[26];
  const float* fc2b = (const float*)d_in[27];
  const float* dcw  = (const float*)d_in[28];
  const float* dcb  = (const float*)d_in[29];

  char* p = (char*)d_ws;
  size_t used = 0;
  auto alloc = [&](size_t bytes) -> char* {
    char* r = p + used;
    used += (bytes + 255) & ~(size_t)255;
    return r;
  };
  float* adjW   = (float*)alloc(GN*4);
  float* dadjW  = (float*)alloc(GN*4);
  float* gW     = (float*)alloc(4*GN*4);
  float* STa    = (float*)alloc(CCH*NNODE*4);
  float* STb    = (float*)alloc(CCH*NNODE*4);
  float* Spart  = (float*)alloc(4*CCH*NNODE*4);
  float* wT5[4]; float* wT3[4];
  short* wp5[4]; short* wp3[4];
  for (int s = 0; s < 4; s++) {
    wT5[s] = (float*)alloc(64*64*5*4);
    wT3[s] = (float*)alloc(64*64*3*4);
    wp5[s] = (short*)alloc(20480*2);
    wp3[s] = (short*)alloc(12288*2);
  }
  short* dcwP   = (short*)alloc(8192*2);
  short* dadjP  = (short*)alloc(33792*2);
  bf16* H1      = (bf16*)alloc(HSZ*2);
  bf16* H2      = (bf16*)alloc(HSZ*2);
  bf16* HA      = (bf16*)alloc(HSZ*2);
  float* h7fA   = (float*)alloc(H7SZ*4);
  float* h7fB   = (float*)alloc(H7SZ*4);
  float* hA7f   = (float*)alloc(H7SZ*4);
  if (used > ws_size) return;  // signature: output stays zero

  float* oute = (float*)d_out;
  float* outo = oute + HSZ;
  float* tail = oute + 2*HSZ;

  dim3 bgrid(NNODE, 4, BBATCH);
  dim3 agrid(448, 4);
  dim3 a7grid(64, 8);
  dim3 mgrid(NNODE, 7, 4);
  dim3 m7grid(NNODE, 4);

  SetupArgs sa;
  for (int s = 0; s < 4; s++) {
    sa.w5[s] = w5[s]; sa.w3[s] = w3[s];
    sa.wT5[s] = wT5[s]; sa.wT3[s] = wT3[s];
    sa.wp5[s] = wp5[s]; sa.wp3[s] = wp3[s];
  }
  sa.dcw = dcw; sa.dcwP = dcwP;
  sa.nv1 = nv1; sa.nv2 = nv2; sa.adj = adjW;
  sa.g = gW;
  k_setup<<<1678, 256, 0, stream>>>(sa);

  auto graph_pipe = [&](float* ST, const float* gstep, float* tailp) {
    k_sredT<<<43, 256, 0, stream>>>(Spart, ST);
    k_gg<<<NNODE, 256, 0, stream>>>(ST, adjW, ggw, ggb, fc0w, fc0b, fc1w, fc1b,
                                    fc2w, fc2b, gstep, a_in, dadjW, tailp);
    k_packD<<<132, 256, 0, stream>>>(dadjW, dadjP);
  };
  auto hA_all = [&](bf16* Hb, float* h7f) {
    k_hA_m<<<agrid, 256, 0, stream>>>(Hb, dadjP, HA);
    k_hA7<<<a7grid, 256, 0, stream>>>(h7f, dadjW, hA7f);
  };
  auto mix_all = [&](bf16* Hb, float* h7f, int epi) {
    k_mix_m<<<mgrid, 256, 0, stream>>>(Hb, HA, dcwP, dcb, x, oute, outo, epi);
    k_mix7<<<m7grid, 256, 0, stream>>>(h7f, hA7f, dcw, dcb, x, oute, outo, epi);
  };

  // step 1: branch(xe) -> x1 ; d = xo*tanh(x1) -> outo
  k_branch<<<bgrid, 256, 0, stream>>>(x, 0, wT5[0], b5[0], wT3[0], b3[0], wp5[0], wp3[0], H1, h7fA, Spart);
  graph_pipe(STa, gW, nullptr);
  hA_all(H1, h7fA);
  mix_all(H1, h7fA, 1);

  // step 2: branch(xo) -> x2 ; c = xe*tanh(x2) -> oute
  k_branch<<<bgrid, 256, 0, stream>>>(x, 1, wT5[1], b5[1], wT3[1], b3[1], wp5[1], wp3[1], H1, h7fA, Spart);
  graph_pipe(STa, gW + GN, nullptr);
  hA_all(H1, h7fA);
  mix_all(H1, h7fA, 2);

  // steps 3 & 4: run both branches BEFORE either epilogue overwrites d_out
  k_branch<<<bgrid, 256, 0, stream>>>(oute, -1, wT5[2], b5[2], wT3[2], b3[2], wp5[2], wp3[2], H1, h7fA, Spart);
  k_sredT<<<43, 256, 0, stream>>>(Spart, STa);
  k_branch<<<bgrid, 256, 0, stream>>>(outo, -1, wT5[3], b5[3], wT3[3], b3[3], wp5[3], wp3[3], H2, h7fB, Spart);
  k_sredT<<<43, 256, 0, stream>>>(Spart, STb);

  // step 3 rest: outo = d - x3
  k_gg<<<NNODE, 256, 0, stream>>>(STa, adjW, ggw, ggb, fc0w, fc0b, fc1w, fc1b,
                                  fc2w, fc2b, gW + 2*GN, a_in, dadjW, nullptr);
  k_packD<<<132, 256, 0, stream>>>(dadjW, dadjP);
  hA_all(H1, h7fA);
  mix_all(H1, h7fA, 3);

  // step 4 rest: oute = c + x4 ; dadj -> tail
  k_gg<<<NNODE, 256, 0, stream>>>(STb, adjW, ggw, ggb, fc0w, fc0b, fc1w, fc1b,
                                  fc2w, fc2b, gW + 3*GN, a_in, dadjW, tail);
  k_packD<<<132, 256, 0, stream>>>(dadjW, dadjP);
  hA_all(H2, h7fB);
  mix_all(H2, h7fB, 4);

  (void)in_sizes; (void)n_in; (void)out_size;
}

// Round 13
// 1221.586 us; speedup vs baseline: 1.2467x; 1.1939x over previous
//
#include <hip/hip_runtime.h>
#include <hip/hip_bf16.h>
#include <cstdint>
#include <cstddef>

using bf16 = __hip_bfloat16;

static constexpr int BBATCH = 8, CCH = 64, NNODE = 170, TT = 256;
static constexpr size_t HSZ  = (size_t)BBATCH * CCH * NNODE * TT;  // 22282240
static constexpr size_t H7SZ = (size_t)CCH * NNODE * TT;           // 2785280
static constexpr int GN = NNODE * NNODE;                           // 28900

typedef __attribute__((ext_vector_type(8))) short short8v;
typedef __attribute__((ext_vector_type(4))) float f32x4;

__device__ __forceinline__ float b2f(bf16 v) { return __bfloat162float(v); }
__device__ __forceinline__ bf16  f2b(float v) { return __float2bfloat16(v); }

union BfU { bf16 h; unsigned short s; };
__device__ __forceinline__ unsigned short bfbits(float v) { BfU u; u.h = f2b(v); return u.s; }
__device__ __forceinline__ unsigned pack2(float a, float b) {
  return ((unsigned)bfbits(b) << 16) | bfbits(a);
}
__device__ __forceinline__ unsigned pks(short lo, short hi) {
  return ((unsigned)(unsigned short)hi << 16) | (unsigned short)lo;
}
__device__ __forceinline__ float shortbf(short s) { BfU u; u.s = (unsigned short)s; return b2f(u.h); }

__device__ __forceinline__ float tanhfast(float v) {
  float e = __expf(2.f * v);
  return 1.f - 2.f / (e + 1.f);
}

// ---------------- threefry2x32 ----------------
__device__ __forceinline__ unsigned rotl32(unsigned v, int d) { return (v << d) | (v >> (32 - d)); }

__device__ void threefry2x32(unsigned k0, unsigned k1, unsigned x0, unsigned x1,
                             unsigned& y0, unsigned& y1) {
  unsigned ks0 = k0, ks1 = k1, ks2 = k0 ^ k1 ^ 0x1BD11BDAu;
  x0 += ks0; x1 += ks1;
  const int ra[4] = {13, 15, 26, 6};
  const int rb[4] = {17, 29, 16, 24};
#pragma unroll
  for (int r = 0; r < 4; r++) { x0 += x1; x1 = rotl32(x1, ra[r]); x1 ^= x0; }
  x0 += ks1; x1 += ks2 + 1u;
#pragma unroll
  for (int r = 0; r < 4; r++) { x0 += x1; x1 = rotl32(x1, rb[r]); x1 ^= x0; }
  x0 += ks2; x1 += ks0 + 2u;
#pragma unroll
  for (int r = 0; r < 4; r++) { x0 += x1; x1 = rotl32(x1, ra[r]); x1 ^= x0; }
  x0 += ks0; x1 += ks1 + 3u;
#pragma unroll
  for (int r = 0; r < 4; r++) { x0 += x1; x1 = rotl32(x1, rb[r]); x1 ^= x0; }
  x0 += ks1; x1 += ks2 + 4u;
#pragma unroll
  for (int r = 0; r < 4; r++) { x0 += x1; x1 = rotl32(x1, ra[r]); x1 ^= x0; }
  x0 += ks2; x1 += ks0 + 5u;
  y0 = x0; y1 = x1;
}

// ---------------- mega setup kernel ----------------
struct SetupArgs {
  const float* w5[4]; const float* w3[4];
  float* wT5[4]; float* wT3[4];
  short* wp5[4]; short* wp3[4];
  const float* dcw; short* dcwP;
  const float* nv1; const float* nv2; float* adj;
  float* g;
};

__global__ __launch_bounds__(256) void k_setup(SetupArgs a) {
  const int blk = blockIdx.x;
  const int tid = threadIdx.x;
  __shared__ float red[256];

  if (blk < 170) {
    const int i = blk, j = tid;
    float val = 0.f, r = -1e30f;
    if (j < NNODE) {
      float acc = 0.f;
      for (int k = 0; k < 10; k++) acc += a.nv1[i*10+k] * a.nv2[k*NNODE+j];
      val = acc > 0.f ? acc : 0.f;
      r = val;
    }
    red[j] = r; __syncthreads();
    for (int s = 128; s; s >>= 1) { if (j < s) red[j] = fmaxf(red[j], red[j+s]); __syncthreads(); }
    float m = red[0]; __syncthreads();
    float e = (j < NNODE) ? expf(val - m) : 0.f;
    red[j] = e; __syncthreads();
    for (int s = 128; s; s >>= 1) { if (j < s) red[j] += red[j+s]; __syncthreads(); }
    if (j < NNODE) a.adj[i*NNODE+j] = e / red[0];
    return;
  }
  if (blk < 622) {
    int idx = (blk - 170) * 256 + tid;
    if (idx >= 4 * GN) return;
    int w = idx / GN, i = idx % GN;
    unsigned k0, k1, y0, y1;
    threefry2x32(0u, 42u, 0u, (unsigned)w, k0, k1);
    threefry2x32(k0, k1, 0u, (unsigned)i, y0, y1);
    unsigned bits = y0 ^ y1;
    unsigned fb = (bits >> 9) | 0x3f800000u;
    float u = __uint_as_float(fb) - 1.0f;
    a.g[idx] = -logf(-logf(u + 1e-20f) + 1e-20f);
    return;
  }
  if (blk < 942) {
    int gi = blk - 622, s = gi / 80;
    int idx = (gi - s*80) * 256 + tid;
    if (idx >= 20480) return;
    int oc = idx / 5, k = idx - oc * 5;
    int o = oc >> 6, c = oc & 63;
    a.wT5[s][(c*5 + k)*64 + o] = a.w5[s][idx];
    return;
  }
  if (blk < 1134) {
    int gi = blk - 942, s = gi / 48;
    int idx = (gi - s*48) * 256 + tid;
    if (idx >= 12288) return;
    int oc = idx / 3, k = idx - oc * 3;
    int o = oc >> 6, c = oc & 63;
    a.wT3[s][(c*3 + k)*64 + o] = a.w3[s][idx];
    return;
  }
  if (blk < 1454) {
    int gi = blk - 1134, s = gi / 80;
    int idx = (gi - s*80) * 256 + tid;
    if (idx >= 20480) return;
    int j = idx & 7, l = (idx >> 3) & 63, mi = (idx >> 9) & 3, ks = (idx >> 11) & 1, k = idx >> 12;
    int o = mi*16 + (l & 15);
    int c = ks*32 + (l >> 4)*8 + j;
    a.wp5[s][idx] = (short)bfbits(a.w5[s][(o*64 + c)*5 + k]);
    return;
  }
  if (blk < 1646) {
    int gi = blk - 1454, s = gi / 48;
    int idx = (gi - s*48) * 256 + tid;
    if (idx >= 12288) return;
    int j = idx & 7, l = (idx >> 3) & 63, mi = (idx >> 9) & 3, ks = (idx >> 11) & 1, k = idx >> 12;
    int o = mi*16 + (l & 15);
    int c = ks*32 + (l >> 4)*8 + j;
    a.wp3[s][idx] = (short)bfbits(a.w3[s][(o*64 + c)*3 + k]);
    return;
  }
  {
    int idx = (blk - 1646) * 256 + tid;
    if (idx >= 8192) return;
    int j = idx & 7, l = (idx >> 3) & 63, mi = (idx >> 9) & 3, kk = idx >> 11;
    int o = mi*16 + (l & 15);
    int c = kk*32 + (l >> 4)*8 + j;
    a.dcwP[idx] = (short)bfbits(a.dcw[o*128 + c]);
  }
}

// ---------------- branch body (shared by merged kernel) ----------------
__device__ void branch_body(int n, int q, int b,
    const float* __restrict__ src, int par,
    const float* __restrict__ wT5, const float* __restrict__ b5,
    const float* __restrict__ wT3, const float* __restrict__ b3,
    const short* __restrict__ wp5, const short* __restrict__ wp3,
    bf16* __restrict__ hout, float* __restrict__ h7f, float* __restrict__ Spart,
    char* lds) {
  const int tid = threadIdx.x;
  const int l = tid & 63;
  const int w = __builtin_amdgcn_readfirstlane(tid >> 6);
  const int t0 = q * 64;

  if (b == 7) {
    float (*xs)[72]  = (float(*)[72])lds;
    float (*h1s)[68] = (float(*)[68])(lds + 18432);
    const int o = l;
    const int base = w * 16;
    const bool w3x = (w == 3);

    for (int i = tid; i < 64 * 70; i += 256) {
      int c = i / 70, pl = i - c * 70;
      int t = t0 + pl - 3; t = t < 0 ? 0 : (t > 255 ? 255 : t);
      size_t sb = ((size_t)7 * 64 + c) * NNODE + n;
      xs[c][pl] = (par >= 0) ? src[sb * 512 + 2 * t + par] : src[sb * 256 + t];
    }
    __syncthreads();

    {
      float acc[16];
#pragma unroll
      for (int tt = 0; tt < 16; tt++) acc[tt] = 0.f;
      float aH0 = 0.f, aH1 = 0.f;
      const float* wp = wT5 + o;
      for (int c = 0; c < 64; c++) {
        float xv[22];
        float4 v0 = *(const float4*)&xs[c][base + 0];
        float4 v1 = *(const float4*)&xs[c][base + 4];
        float4 v2 = *(const float4*)&xs[c][base + 8];
        float4 v3 = *(const float4*)&xs[c][base + 12];
        float4 v4 = *(const float4*)&xs[c][base + 16];
        xv[0]=v0.x; xv[1]=v0.y; xv[2]=v0.z; xv[3]=v0.w;
        xv[4]=v1.x; xv[5]=v1.y; xv[6]=v1.z; xv[7]=v1.w;
        xv[8]=v2.x; xv[9]=v2.y; xv[10]=v2.z; xv[11]=v2.w;
        xv[12]=v3.x; xv[13]=v3.y; xv[14]=v3.z; xv[15]=v3.w;
        xv[16]=v4.x; xv[17]=v4.y; xv[18]=v4.z; xv[19]=v4.w;
        if (w3x) { float2 vt = *(const float2*)&xs[c][68]; xv[20]=vt.x; xv[21]=vt.y; }
        float w0 = wp[0], w1 = wp[64], w2 = wp[128], w3_ = wp[192], w4 = wp[256];
        wp += 320;
#pragma unroll
        for (int tt = 0; tt < 16; tt++)
          acc[tt] += w0*xv[tt] + w1*xv[tt+1] + w2*xv[tt+2] + w3_*xv[tt+3] + w4*xv[tt+4];
        if (w3x) {
          aH0 += w0*xv[16] + w1*xv[17] + w2*xv[18] + w3_*xv[19] + w4*xv[20];
          aH1 += w0*xv[17] + w1*xv[18] + w2*xv[19] + w3_*xv[20] + w4*xv[21];
        }
      }
      float bias = b5[o];
#pragma unroll
      for (int tt = 0; tt < 16; tt++) {
        float v = acc[tt] + bias;
        h1s[o][base + tt] = v >= 0.f ? v : 0.01f * v;
      }
      if (w3x) {
        float u0 = aH0 + bias, u1 = aH1 + bias;
        h1s[o][64] = u0 >= 0.f ? u0 : 0.01f * u0;
        h1s[o][65] = u1 >= 0.f ? u1 : 0.01f * u1;
      }
    }
    __syncthreads();

    {
      float acc[16];
#pragma unroll
      for (int tt = 0; tt < 16; tt++) acc[tt] = 0.f;
      const float* wp = wT3 + o;
      for (int c = 0; c < 64; c++) {
        float hv[18];
        float4 v0 = *(const float4*)&h1s[c][base + 0];
        float4 v1 = *(const float4*)&h1s[c][base + 4];
        float4 v2 = *(const float4*)&h1s[c][base + 8];
        float4 v3 = *(const float4*)&h1s[c][base + 12];
        float4 v4 = *(const float4*)&h1s[c][base + 16];
        hv[0]=v0.x; hv[1]=v0.y; hv[2]=v0.z; hv[3]=v0.w;
        hv[4]=v1.x; hv[5]=v1.y; hv[6]=v1.z; hv[7]=v1.w;
        hv[8]=v2.x; hv[9]=v2.y; hv[10]=v2.z; hv[11]=v2.w;
        hv[12]=v3.x; hv[13]=v3.y; hv[14]=v3.z; hv[15]=v3.w;
        hv[16]=v4.x; hv[17]=v4.y;
        float w0 = wp[0], w1 = wp[64], w2 = wp[128];
        wp += 192;
#pragma unroll
        for (int tt = 0; tt < 16; tt++)
          acc[tt] += w0*hv[tt] + w1*hv[tt+1] + w2*hv[tt+2];
      }
      float bias = b3[o];
#pragma unroll
      for (int tt = 0; tt < 16; tt++) acc[tt] = tanhf(acc[tt] + bias);
      __syncthreads();
#pragma unroll
      for (int tt = 0; tt < 16; tt++) xs[o][base + tt] = acc[tt];
    }
    __syncthreads();

    {
      const int ro = tid >> 2, rq = tid & 3;
      float4 v0 = *(const float4*)&xs[ro][rq*16 + 0];
      float4 v1 = *(const float4*)&xs[ro][rq*16 + 4];
      float4 v2 = *(const float4*)&xs[ro][rq*16 + 8];
      float4 v3 = *(const float4*)&xs[ro][rq*16 + 12];
      float* dst = h7f + ((size_t)ro * NNODE + n) * TT + t0 + rq*16;
      *(float4*)&dst[0] = v0; *(float4*)&dst[4] = v1;
      *(float4*)&dst[8] = v2; *(float4*)&dst[12] = v3;
      float s = v0.x+v0.y+v0.z+v0.w + v1.x+v1.y+v1.z+v1.w
              + v2.x+v2.y+v2.z+v2.w + v3.x+v3.y+v3.z+v3.w;
      s += __shfl_xor(s, 1, 4);
      s += __shfl_xor(s, 2, 4);
      if (rq == 0) Spart[(q * 64 + ro) * NNODE + n] = s;
    }
    return;
  }

  // bf16 MFMA path (b < 7)
  const int mi = w;

  for (int it = 0; it < 16; it++) {
    int c = it * 4 + w;
    int t = t0 + l - 3; t = t < 0 ? 0 : (t > 255 ? 255 : t);
    size_t sb = ((size_t)b * 64 + c) * NNODE + n;
    float v = (par >= 0) ? src[sb * 512 + 2 * t + par] : src[sb * 256 + t];
    *(short*)(lds + l*128 + ((2*c) ^ ((l & 7) << 4))) = (short)bfbits(v);
  }
  for (int i = tid; i < 6 * 64; i += 256) {
    int tr = 64 + (i >> 6);
    int c = i & 63;
    int t = t0 + tr - 3; if (t > 255) t = 255;
    size_t sb = ((size_t)b * 64 + c) * NNODE + n;
    float v = (par >= 0) ? src[sb * 512 + 2 * t + par] : src[sb * 256 + t];
    *(short*)(lds + tr*128 + ((2*c) ^ ((tr & 7) << 4))) = (short)bfbits(v);
  }
  __syncthreads();

  f32x4 acc[5];
#pragma unroll
  for (int i = 0; i < 5; i++) acc[i] = (f32x4){0.f, 0.f, 0.f, 0.f};
  for (int k = 0; k < 5; k++) {
#pragma unroll
    for (int ks = 0; ks < 2; ks++) {
      short8v af = *(const short8v*)(wp5 + (size_t)((((k*2 + ks)*4 + mi)*64 + l) * 8));
      const int c0 = ks*32 + (l >> 4)*8;
#pragma unroll
      for (int ni = 0; ni < 5; ni++) {
        int tr = ni*16 + (l & 15) + k;
        short8v bf = *(const short8v*)(lds + tr*128 + ((2*c0) ^ ((tr & 7) << 4)));
        acc[ni] = __builtin_amdgcn_mfma_f32_16x16x32_bf16(af, bf, acc[ni], 0, 0, 0);
      }
    }
  }
  {
    const int o0 = mi*16 + ((l >> 4) << 2);
    float4 bv = *(const float4*)&b5[o0];
    float bb[4] = {bv.x, bv.y, bv.z, bv.w};
#pragma unroll
    for (int ni = 0; ni < 4; ni++) {
      int tr = ni*16 + (l & 15);
      float v[4];
#pragma unroll
      for (int r = 0; r < 4; r++) {
        float u = acc[ni][r] + bb[r];
        v[r] = u >= 0.f ? u : 0.01f * u;
      }
      int colb = (2*o0) ^ ((tr & 7) << 4);
      *(uint2*)(lds + 10752 + tr*128 + colb) = make_uint2(pack2(v[0], v[1]), pack2(v[2], v[3]));
    }
    if ((l & 15) < 2) {
      int tr = 64 + (l & 15);
      float v[4];
#pragma unroll
      for (int r = 0; r < 4; r++) {
        float u = acc[4][r] + bb[r];
        v[r] = u >= 0.f ? u : 0.01f * u;
      }
      int colb = (2*o0) ^ ((tr & 7) << 4);
      *(uint2*)(lds + 10752 + tr*128 + colb) = make_uint2(pack2(v[0], v[1]), pack2(v[2], v[3]));
    }
  }
  __syncthreads();

  f32x4 acc3[4];
#pragma unroll
  for (int i = 0; i < 4; i++) acc3[i] = (f32x4){0.f, 0.f, 0.f, 0.f};
  for (int k = 0; k < 3; k++) {
#pragma unroll
    for (int ks = 0; ks < 2; ks++) {
      short8v af = *(const short8v*)(wp3 + (size_t)((((k*2 + ks)*4 + mi)*64 + l) * 8));
      const int c0 = ks*32 + (l >> 4)*8;
#pragma unroll
      for (int ni = 0; ni < 4; ni++) {
        int tr = ni*16 + (l & 15) + k;
        short8v bf = *(const short8v*)(lds + 10752 + tr*128 + ((2*c0) ^ ((tr & 7) << 4)));
        acc3[ni] = __builtin_amdgcn_mfma_f32_16x16x32_bf16(af, bf, acc3[ni], 0, 0, 0);
      }
    }
  }
  {
    const int o0 = mi*16 + ((l >> 4) << 2);
    float4 bv = *(const float4*)&b3[o0];
    float bb[4] = {bv.x, bv.y, bv.z, bv.w};
#pragma unroll
    for (int ni = 0; ni < 4; ni++) {
      int t = ni*16 + (l & 15);
#pragma unroll
      for (int r = 0; r < 4; r++) {
        float v = tanhfast(acc3[ni][r] + bb[r]);
        *(short*)(lds + (o0 + r)*144 + t*2) = (short)bfbits(v);
      }
    }
  }
  __syncthreads();

  {
    const int ro = tid >> 2, rq = tid & 3;
    uint4 p0 = *(const uint4*)(lds + ro*144 + rq*32);
    uint4 p1 = *(const uint4*)(lds + ro*144 + rq*32 + 16);
    bf16* dst = hout + (((size_t)b * 64 + ro) * NNODE + n) * TT + t0 + rq*16;
    *(uint4*)&dst[0] = p0;
    *(uint4*)&dst[8] = p1;
  }
}

// merged 2-step branch: grid (170, 4, 16); z>>3 = step, z&7 = b
__global__ __launch_bounds__(256) void k_branch2(
    const float* src0, const float* src1, int par0, int par1,
    const float* wT5_0, const float* wT5_1, const float* b5_0, const float* b5_1,
    const float* wT3_0, const float* wT3_1, const float* b3_0, const float* b3_1,
    const short* wp5_0, const short* wp5_1, const short* wp3_0, const short* wp3_1,
    bf16* hout0, bf16* hout1, float* h7f0, float* h7f1, float* Sp0, float* Sp1) {
  __shared__ char lds[35840];
  const int step = blockIdx.z >> 3;
  const int b = blockIdx.z & 7;
  branch_body(blockIdx.x, blockIdx.y, b,
              step ? src1 : src0, step ? par1 : par0,
              step ? wT5_1 : wT5_0, step ? b5_1 : b5_0,
              step ? wT3_1 : wT3_0, step ? b3_1 : b3_0,
              step ? wp5_1 : wp5_0, step ? wp3_1 : wp3_0,
              step ? hout1 : hout0, step ? h7f1 : h7f0, step ? Sp1 : Sp0, lds);
}

// merged sredT: 86 blocks
__global__ __launch_bounds__(256) void k_sredT2(const float* __restrict__ Sp0, const float* __restrict__ Sp1,
                                                float* __restrict__ ST0, float* __restrict__ ST1) {
  int gidx = blockIdx.x * 256 + threadIdx.x;
  int step = gidx >= CCH*NNODE;
  int idx = gidx - step * CCH*NNODE;
  if (idx >= CCH * NNODE) return;
  const float* Sp = step ? Sp1 : Sp0;
  float* ST = step ? ST1 : ST0;
  int nn = idx >> 6, c = idx & 63;
  float acc = 0.f;
#pragma unroll
  for (int qq = 0; qq < 4; qq++) acc += Sp[(qq * 64 + c) * NNODE + nn];
  ST[idx] = acc;
}

// merged graph-gen: grid (170, 2)
__global__ __launch_bounds__(256) void k_gg2(const float* __restrict__ ST0, const float* __restrict__ ST1,
    const float* __restrict__ adj,
    const float* __restrict__ ggw, const float* __restrict__ ggb,
    const float* __restrict__ fc0w, const float* __restrict__ fc0b,
    const float* __restrict__ fc1w, const float* __restrict__ fc1b,
    const float* __restrict__ fc2w, const float* __restrict__ fc2b,
    const float* __restrict__ g0, const float* __restrict__ g1,
    const float* __restrict__ a_in,
    float* __restrict__ dadj0, float* __restrict__ dadj1,
    float* __restrict__ tail0, float* __restrict__ tail1) {
  const int i = blockIdx.x;
  const int step = blockIdx.y;
  const float* ST = step ? ST1 : ST0;
  const float* g = step ? g1 : g0;
  float* dadj = step ? dadj1 : dadj0;
  float* out_tail = step ? tail1 : tail0;
  const int tid = threadIdx.x;
  __shared__ float s1[64], sc[64], h0r[64];
  __shared__ float a1r[NNODE];
  __shared__ float a2r[340];
  __shared__ float vred[256];
  __shared__ int ired[256];
  if (tid < 64) {
    const int c = tid;
    float acc = 0.f;
    for (int nn = 0; nn < NNODE; nn++) acc += ST[nn*64 + c] * adj[nn*NNODE + i];
    s1[c] = acc;
    sc[c] = ST[i*64 + c];
  }
  __syncthreads();
  if (tid < 64) {
    const int o = tid;
    float acc = 256.f * ggb[o];
    for (int c = 0; c < 64; c++)
      acc += ggw[o*128 + c] * sc[c] + ggw[o*128 + 64 + c] * s1[c];
    h0r[o] = acc;
  }
  __syncthreads();
  if (tid < NNODE) {
    float acc = fc0b[tid];
    for (int o = 0; o < 64; o++) acc += h0r[o] * fc0w[tid*64 + o];
    a1r[tid] = tanhf(acc);
  }
  __syncthreads();
  for (int j = tid; j < 340; j += 256) {
    float acc = fc1b[j];
    for (int k = 0; k < NNODE; k++) acc += a1r[k] * fc1w[j*NNODE + k];
    a2r[j] = tanhf(acc);
  }
  __syncthreads();
  float v = -1e30f;
  if (tid < NNODE) {
    float acc = fc2b[tid];
    for (int k = 0; k < 340; k++) acc += a2r[k] * fc2w[tid*340 + k];
    v = tanhf(acc) + g[i*NNODE + tid];
  }
  vred[tid] = v; ired[tid] = tid;
  __syncthreads();
  for (int s = 128; s; s >>= 1) {
    if (tid < s) {
      if (vred[tid+s] > vred[tid]) { vred[tid] = vred[tid+s]; ired[tid] = ired[tid+s]; }
    }
    __syncthreads();
  }
  int jmax = ired[0];
  float a = a_in[0];
  if (tid < NNODE) {
    float la = (tid == jmax && jmax != i) ? 1.f : 0.f;
    float dv = la * a + adj[i*NNODE + tid] * (1.f - a);
    dadj[i*NNODE + tid] = dv;
    if (out_tail) out_tail[i*NNODE + tid] = dv;
  }
}

// merged packD: 264 blocks
__global__ __launch_bounds__(256) void k_packD2(const float* __restrict__ dadj0, const float* __restrict__ dadj1,
                                                short* __restrict__ out0, short* __restrict__ out1) {
  int gidx = blockIdx.x * 256 + threadIdx.x;
  int step = gidx >= 33792;
  int idx = gidx - step * 33792;
  if (idx >= 33792) return;
  const float* dadj = step ? dadj1 : dadj0;
  short* out = step ? out1 : out0;
  int j = idx & 7, l = (idx >> 3) & 63;
  int g = idx >> 9;
  int ks = g % 6, mi = g / 6;
  int m = mi*16 + (l & 15);
  int n = ks*32 + (l >> 4)*8 + j;
  float v = (m < NNODE && n < NNODE) ? dadj[n*NNODE + m] : 0.f;
  out[idx] = (short)bfbits(v);
}

// merged hA MFMA: grid (448, 4, steps)
__global__ __launch_bounds__(256) void k_hA_m2(const bf16* __restrict__ h0, const short* __restrict__ dP0, bf16* __restrict__ hA0,
                                               const bf16* __restrict__ h1, const short* __restrict__ dP1, bf16* __restrict__ hA1) {
  const int step = blockIdx.z;
  const bf16* h = step ? h1 : h0;
  const short* dP = step ? dP1 : dP0;
  bf16* hA = step ? hA1 : hA0;
  const int bc = blockIdx.x, tq = blockIdx.y;
  const int tid = threadIdx.x;
  const int l = tid & 63;
  const int w = __builtin_amdgcn_readfirstlane(tid >> 6);
  const int t0 = tq * 64;
  __shared__ char lds[25600];

  const bf16* hp = h + (size_t)bc * NNODE * TT;
  for (int i = tid; i < 170*64; i += 256) {
    int n = i >> 6, t = i & 63;
    *(short*)(lds + t*400 + ((2*n) ^ ((t & 7) << 4))) = *(const short*)&hp[(size_t)n * TT + t0 + t];
  }
  for (int i = tid; i < 22*64; i += 256) {
    int n = 170 + (i >> 6), t = i & 63;
    *(short*)(lds + t*400 + ((2*n) ^ ((t & 7) << 4))) = 0;
  }
  __syncthreads();

  f32x4 acc[11];
#pragma unroll
  for (int i = 0; i < 11; i++) acc[i] = (f32x4){0.f, 0.f, 0.f, 0.f};
  const int tr = w*16 + (l & 15);
#pragma unroll
  for (int ks = 0; ks < 6; ks++) {
    const int n0 = ks*32 + (l >> 4)*8;
    short8v bf = *(const short8v*)(lds + tr*400 + ((2*n0) ^ ((tr & 7) << 4)));
#pragma unroll
    for (int mi = 0; mi < 11; mi++) {
      short8v af = *(const short8v*)(dP + (size_t)(((mi*6 + ks)*64 + l) * 8));
      acc[mi] = __builtin_amdgcn_mfma_f32_16x16x32_bf16(af, bf, acc[mi], 0, 0, 0);
    }
  }

  bf16* dst = hA + (size_t)bc * NNODE * TT + t0 + w*16 + (l & 15);
#pragma unroll
  for (int mi = 0; mi < 11; mi++) {
#pragma unroll
    for (int r = 0; r < 4; r++) {
      int m = mi*16 + ((l >> 4) << 2) + r;
      if (m < NNODE) dst[(size_t)m * TT] = f2b(acc[mi][r]);
    }
  }
}

// merged hA7: grid (64, 8, steps)
__global__ __launch_bounds__(256) void k_hA7_2(const float* __restrict__ h7f0, const float* __restrict__ dadj0, float* __restrict__ hA7f0,
                                               const float* __restrict__ h7f1, const float* __restrict__ dadj1, float* __restrict__ hA7f1) {
  const int step = blockIdx.z;
  const float* h7f = step ? h7f1 : h7f0;
  const float* dadj = step ? dadj1 : dadj0;
  float* hA7f = step ? hA7f1 : hA7f0;
  const int c = blockIdx.x, tq = blockIdx.y;
  const int t0 = tq * 32;
  const int tid = threadIdx.x;
  const int lane = tid & 63;
  const int w = __builtin_amdgcn_readfirstlane(tid >> 6);
  __shared__ float hs[170][33];
  for (int i = tid; i < 170*32; i += 256) {
    int nn = i >> 5, tl = i & 31;
    hs[nn][tl] = h7f[((size_t)c * NNODE + nn) * TT + t0 + tl];
  }
  __syncthreads();
  float acc0[8], acc1[8], acc2[8];
#pragma unroll
  for (int tt = 0; tt < 8; tt++) { acc0[tt] = 0.f; acc1[tt] = 0.f; acc2[tt] = 0.f; }
  const int toff = w * 8;
  for (int nn = 0; nn < NNODE; nn++) {
    float hv[8];
#pragma unroll
    for (int tt = 0; tt < 8; tt++) hv[tt] = hs[nn][toff + tt];
    const float* dr = &dadj[nn * NNODE];
    float w0 = dr[lane];
    float w1 = dr[64 + lane];
    float w2 = (lane < 42) ? dr[128 + lane] : 0.f;
#pragma unroll
    for (int tt = 0; tt < 8; tt++) {
      acc0[tt] += w0 * hv[tt];
      acc1[tt] += w1 * hv[tt];
      acc2[tt] += w2 * hv[tt];
    }
  }
  __syncthreads();
#pragma unroll
  for (int tt = 0; tt < 8; tt++) {
    hs[lane][toff + tt] = acc0[tt];
    hs[64 + lane][toff + tt] = acc1[tt];
    if (lane < 42) hs[128 + lane][toff + tt] = acc2[tt];
  }
  __syncthreads();
  if (tid < NNODE) {
    float* dst = hA7f + ((size_t)c * NNODE + tid) * TT + t0;
#pragma unroll
    for (int j = 0; j < 8; j++)
      *(float4*)&dst[j*4] = make_float4(hs[tid][j*4], hs[tid][j*4+1], hs[tid][j*4+2], hs[tid][j*4+3]);
  }
}

// merged mix MFMA: grid (170, 7*steps, 4); y%7 = b, y/7 = step; epi = epiBase + step
__global__ __launch_bounds__(256) void k_mix_m2(const bf16* __restrict__ h0, const bf16* __restrict__ hA0,
                                                const bf16* __restrict__ h1, const bf16* __restrict__ hA1,
                                                const short* __restrict__ dcwP, const float* __restrict__ dcb,
                                                const float* __restrict__ x,
                                                float* __restrict__ oute, float* __restrict__ outo, int epiBase) {
  const int n = blockIdx.x, tq = blockIdx.z;
  const int b = blockIdx.y % 7;
  const int step = blockIdx.y / 7;
  const bf16* h = step ? h1 : h0;
  const bf16* hA = step ? hA1 : hA0;
  const int epi = epiBase + step;
  const int tid = threadIdx.x;
  const int l = tid & 63;
  const int mi = __builtin_amdgcn_readfirstlane(tid >> 6);
  const int t0 = tq * 64;
  __shared__ char lds[16384];

#pragma unroll
  for (int it = 0; it < 8; it++) {
    int c0 = it * 8 + mi * 2;
    size_t off = (((size_t)b * 64 + c0) * NNODE + n) * TT + t0 + l;
    size_t off1 = off + (size_t)NNODE * TT;
    *(unsigned*)(lds + l*256 + ((2*c0) ^ ((l & 7) << 4))) =
        pks(*(const short*)&h[off], *(const short*)&h[off1]);
    *(unsigned*)(lds + l*256 + ((2*(64 + c0)) ^ ((l & 7) << 4))) =
        pks(*(const short*)&hA[off], *(const short*)&hA[off1]);
  }
  __syncthreads();

  f32x4 acc[4];
#pragma unroll
  for (int i = 0; i < 4; i++) acc[i] = (f32x4){0.f, 0.f, 0.f, 0.f};
#pragma unroll
  for (int kk = 0; kk < 4; kk++) {
    short8v af = *(const short8v*)(dcwP + (size_t)(((kk*4 + mi)*64 + l) * 8));
    const int c0 = kk*32 + (l >> 4)*8;
#pragma unroll
    for (int ni = 0; ni < 4; ni++) {
      int tr = ni*16 + (l & 15);
      short8v bf = *(const short8v*)(lds + tr*256 + ((2*c0) ^ ((tr & 7) << 4)));
      acc[ni] = __builtin_amdgcn_mfma_f32_16x16x32_bf16(af, bf, acc[ni], 0, 0, 0);
    }
  }

  const int o0 = mi*16 + ((l >> 4) << 2);
  float dcb4[4];
#pragma unroll
  for (int r = 0; r < 4; r++) dcb4[r] = dcb[o0 + r];
#pragma unroll
  for (int ni = 0; ni < 4; ni++) {
    int t = ni*16 + (l & 15);
#pragma unroll
    for (int r = 0; r < 4; r++) {
      const int o = o0 + r;
      float hres = shortbf(*(const short*)(lds + t*256 + ((2*o) ^ ((t & 7) << 4))));
      float v = acc[ni][r] + hres + dcb4[r];
      size_t oidx = (((size_t)b * 64 + o) * NNODE + n) * TT + t0 + t;
      if (epi == 1) {
        outo[oidx] = x[(((size_t)b * 64 + o) * NNODE + n) * 512 + 2*(t0 + t) + 1] * tanhfast(v);
      } else if (epi == 2) {
        oute[oidx] = x[(((size_t)b * 64 + o) * NNODE + n) * 512 + 2*(t0 + t)] * tanhfast(v);
      } else if (epi == 3) {
        outo[oidx] -= v;
      } else {
        oute[oidx] += v;
      }
    }
  }
}

// merged mix7: grid (170, 4*steps); y&3 = tq, y>>2 = step
__global__ __launch_bounds__(256) void k_mix7_2(const float* __restrict__ h7f0, const float* __restrict__ hA7f0,
                                                const float* __restrict__ h7f1, const float* __restrict__ hA7f1,
                                                const float* __restrict__ dcw, const float* __restrict__ dcb,
                                                const float* __restrict__ x,
                                                float* __restrict__ oute, float* __restrict__ outo, int epiBase) {
  const int n = blockIdx.x;
  const int tq = blockIdx.y & 3;
  const int step = blockIdx.y >> 2;
  const float* h7f = step ? h7f1 : h7f0;
  const float* hA7f = step ? hA7f1 : hA7f0;
  const int epi = epiBase + step;
  const int tid = threadIdx.x;
  const int lane = tid & 63;
  const int w = __builtin_amdgcn_readfirstlane(tid >> 6);
  const int t = tq * 64 + lane;
  __shared__ float wTs[128][64];
  __shared__ float hsf[64][64];
  __shared__ float hasf[64][64];
  for (int i = tid; i < 8192; i += 256) {
    int o_ = i & 63, cf_ = i >> 6;
    wTs[cf_][o_] = dcw[o_*128 + cf_];
  }
  for (int i = tid; i < 4096; i += 256) {
    int c = i >> 6, tl = i & 63;
    size_t off = ((size_t)c * NNODE + n) * TT + tq * 64 + tl;
    hsf[c][tl] = h7f[off];
    hasf[c][tl] = hA7f[off];
  }
  __syncthreads();
  const int o0 = w * 16;
  float acc[16];
#pragma unroll
  for (int oo = 0; oo < 16; oo++) acc[oo] = 0.f;
  for (int cc = 0; cc < 64; cc++) {
    float hv = hsf[cc][lane];
    float hav = hasf[cc][lane];
    float4 wh0 = *(const float4*)&wTs[cc][o0 + 0];
    float4 wh1 = *(const float4*)&wTs[cc][o0 + 4];
    float4 wh2 = *(const float4*)&wTs[cc][o0 + 8];
    float4 wh3 = *(const float4*)&wTs[cc][o0 + 12];
    float4 wa0 = *(const float4*)&wTs[64 + cc][o0 + 0];
    float4 wa1 = *(const float4*)&wTs[64 + cc][o0 + 4];
    float4 wa2 = *(const float4*)&wTs[64 + cc][o0 + 8];
    float4 wa3 = *(const float4*)&wTs[64 + cc][o0 + 12];
    acc[0]  += wh0.x*hv + wa0.x*hav;  acc[1]  += wh0.y*hv + wa0.y*hav;
    acc[2]  += wh0.z*hv + wa0.z*hav;  acc[3]  += wh0.w*hv + wa0.w*hav;
    acc[4]  += wh1.x*hv + wa1.x*hav;  acc[5]  += wh1.y*hv + wa1.y*hav;
    acc[6]  += wh1.z*hv + wa1.z*hav;  acc[7]  += wh1.w*hv + wa1.w*hav;
    acc[8]  += wh2.x*hv + wa2.x*hav;  acc[9]  += wh2.y*hv + wa2.y*hav;
    acc[10] += wh2.z*hv + wa2.z*hav;  acc[11] += wh2.w*hv + wa2.w*hav;
    acc[12] += wh3.x*hv + wa3.x*hav;  acc[13] += wh3.y*hv + wa3.y*hav;
    acc[14] += wh3.z*hv + wa3.z*hav;  acc[15] += wh3.w*hv + wa3.w*hav;
  }
#pragma unroll
  for (int oo = 0; oo < 16; oo++) {
    const int o = o0 + oo;
    float v = acc[oo] + hsf[o][lane] + dcb[o];
    size_t oidx = (((size_t)7 * 64 + o) * NNODE + n) * TT + t;
    if (epi == 1) {
      outo[oidx] = x[(((size_t)7 * 64 + o) * NNODE + n) * 512 + 2*t + 1] * tanhf(v);
    } else if (epi == 2) {
      oute[oidx] = x[(((size_t)7 * 64 + o) * NNODE + n) * 512 + 2*t] * tanhf(v);
    } else if (epi == 3) {
      outo[oidx] -= v;
    } else {
      oute[oidx] += v;
    }
  }
}

// ---------------- host ----------------
extern "C" void kernel_launch(void* const* d_in, const int* in_sizes, int n_in,
                              void* d_out, int out_size, void* d_ws, size_t ws_size,
                              hipStream_t stream) {
  const float* x    = (const float*)d_in[0];
  const float* nv1  = (const float*)d_in[1];
  const float* nv2  = (const float*)d_in[2];
  const float* a_in = (const float*)d_in[3];
  const float *w5[4], *b5[4], *w3[4], *b3[4];
  for (int s = 0; s < 4; s++) {
    w5[s] = (const float*)d_in[4 + 4*s];
    b5[s] = (const float*)d_in[5 + 4*s];
    w3[s] = (const float*)d_in[6 + 4*s];
    b3[s] = (const float*)d_in[7 + 4*s];
  }
  const float* ggw  = (const float*)d_in[20];
  const float* ggb  = (const float*)d_in[21];
  const float* fc0w = (const float*)d_in[22];
  const float* fc0b = (const float*)d_in[23];
  const float* fc1w = (const float*)d_in[24];
  const float* fc1b = (const float*)d_in[25];
  const float* fc2w = (const float*)d_in[26];
  const float* fc2b = (const float*)d_in[27];
  const float* dcw  = (const float*)d_in[28];
  const float* dcb  = (const float*)d_in[29];

  char* p = (char*)d_ws;
  size_t used = 0;
  auto alloc = [&](size_t bytes) -> char* {
    char* r = p + used;
    used += (bytes + 255) & ~(size_t)255;
    return r;
  };
  float* adjW   = (float*)alloc(GN*4);
  float* dadjA  = (float*)alloc(GN*4);
  float* dadjB  = (float*)alloc(GN*4);
  float* gW     = (float*)alloc(4*GN*4);
  float* STa    = (float*)alloc(CCH*NNODE*4);
  float* STb    = (float*)alloc(CCH*NNODE*4);
  float* SpA    = (float*)alloc(4*CCH*NNODE*4);
  float* SpB    = (float*)alloc(4*CCH*NNODE*4);
  float* wT5[4]; float* wT3[4];
  short* wp5[4]; short* wp3[4];
  for (int s = 0; s < 4; s++) {
    wT5[s] = (float*)alloc(64*64*5*4);
    wT3[s] = (float*)alloc(64*64*3*4);
    wp5[s] = (short*)alloc(20480*2);
    wp3[s] = (short*)alloc(12288*2);
  }
  short* dcwP   = (short*)alloc(8192*2);
  short* dPA    = (short*)alloc(33792*2);
  short* dPB    = (short*)alloc(33792*2);
  bf16* H1      = (bf16*)alloc(HSZ*2);
  bf16* H2      = (bf16*)alloc(HSZ*2);
  bf16* HAa     = (bf16*)alloc(HSZ*2);
  float* h7fA   = (float*)alloc(H7SZ*4);
  float* h7fB   = (float*)alloc(H7SZ*4);
  float* hA7fA  = (float*)alloc(H7SZ*4);
  if (used > ws_size) return;  // core allocation must fit (signature: zero output)

  // optional second hA buffers (merged-steps mode)
  bf16* HAb; float* hA7fB; bool merged;
  {
    size_t need = used + ((HSZ*2 + 255) & ~(size_t)255) + ((H7SZ*4 + 255) & ~(size_t)255);
    if (need <= ws_size) {
      HAb   = (bf16*)alloc(HSZ*2);
      hA7fB = (float*)alloc(H7SZ*4);
      merged = true;
    } else {
      HAb = HAa; hA7fB = hA7fA; merged = false;
    }
  }

  float* oute = (float*)d_out;
  float* outo = oute + HSZ;
  float* tail = oute + 2*HSZ;

  SetupArgs sa;
  for (int s = 0; s < 4; s++) {
    sa.w5[s] = w5[s]; sa.w3[s] = w3[s];
    sa.wT5[s] = wT5[s]; sa.wT3[s] = wT3[s];
    sa.wp5[s] = wp5[s]; sa.wp3[s] = wp3[s];
  }
  sa.dcw = dcw; sa.dcwP = dcwP;
  sa.nv1 = nv1; sa.nv2 = nv2; sa.adj = adjW;
  sa.g = gW;
  k_setup<<<1678, 256, 0, stream>>>(sa);

  dim3 bgrid2(NNODE, 4, 16);

  auto phase = [&](const float* srcA, const float* srcB, int parA, int parB,
                   int sA, int sB, const float* gA, const float* gB,
                   float* tailB, int epiBase) {
    k_branch2<<<bgrid2, 256, 0, stream>>>(srcA, srcB, parA, parB,
        wT5[sA], wT5[sB], b5[sA], b5[sB], wT3[sA], wT3[sB], b3[sA], b3[sB],
        wp5[sA], wp5[sB], wp3[sA], wp3[sB],
        H1, H2, h7fA, h7fB, SpA, SpB);
    k_sredT2<<<86, 256, 0, stream>>>(SpA, SpB, STa, STb);
    k_gg2<<<dim3(NNODE, 2), 256, 0, stream>>>(STa, STb, adjW, ggw, ggb,
        fc0w, fc0b, fc1w, fc1b, fc2w, fc2b, gA, gB, a_in,
        dadjA, dadjB, nullptr, tailB);
    k_packD2<<<264, 256, 0, stream>>>(dadjA, dadjB, dPA, dPB);
    if (merged) {
      k_hA_m2<<<dim3(448, 4, 2), 256, 0, stream>>>(H1, dPA, HAa, H2, dPB, HAb);
      k_hA7_2<<<dim3(64, 8, 2), 256, 0, stream>>>(h7fA, dadjA, hA7fA, h7fB, dadjB, hA7fB);
      k_mix_m2<<<dim3(NNODE, 14, 4), 256, 0, stream>>>(H1, HAa, H2, HAb, dcwP, dcb, x, oute, outo, epiBase);
      k_mix7_2<<<dim3(NNODE, 8), 256, 0, stream>>>(h7fA, hA7fA, h7fB, hA7fB, dcw, dcb, x, oute, outo, epiBase);
    } else {
      // step A
      k_hA_m2<<<dim3(448, 4, 1), 256, 0, stream>>>(H1, dPA, HAa, H1, dPA, HAa);
      k_hA7_2<<<dim3(64, 8, 1), 256, 0, stream>>>(h7fA, dadjA, hA7fA, h7fA, dadjA, hA7fA);
      k_mix_m2<<<dim3(NNODE, 7, 4), 256, 0, stream>>>(H1, HAa, H1, HAa, dcwP, dcb, x, oute, outo, epiBase);
      k_mix7_2<<<dim3(NNODE, 4), 256, 0, stream>>>(h7fA, hA7fA, h7fA, hA7fA, dcw, dcb, x, oute, outo, epiBase);
      // step B
      k_hA_m2<<<dim3(448, 4, 1), 256, 0, stream>>>(H2, dPB, HAa, H2, dPB, HAa);
      k_hA7_2<<<dim3(64, 8, 1), 256, 0, stream>>>(h7fB, dadjB, hA7fA, h7fB, dadjB, hA7fA);
      k_mix_m2<<<dim3(NNODE, 7, 4), 256, 0, stream>>>(H2, HAa, H2, HAa, dcwP, dcb, x, oute, outo, epiBase + 1);
      k_mix7_2<<<dim3(NNODE, 4), 256, 0, stream>>>(h7fB, hA7fA, h7fB, hA7fA, dcw, dcb, x, oute, outo, epiBase + 1);
    }
  };

  // Phase A: steps 1 (xe -> d in outo) and 2 (xo -> c in oute)
  phase(x, x, 0, 1, 0, 1, gW, gW + GN, nullptr, 1);

  // Phase B: steps 3 (oute -> outo -= x3) and 4 (outo -> oute += x4; dadj tail)
  phase(oute, outo, -1, -1, 2, 3, gW + 2*GN, gW + 3*GN, tail, 3);

  (void)in_sizes; (void)n_in; (void)out_size;
}